// Round 9
// baseline (196.833 us; speedup 1.0000x reference)
//
#include <hip/hip_runtime.h>
#include <hip/hip_cooperative_groups.h>
#include <math.h>

namespace cg = cooperative_groups;

#define N_NODES 50000
#define IN_CH   128
#define TOT_CH  128          // HEADS*OUT_CH
#define NEDGE   800000
#define ETOT    (NEDGE + N_NODES)
#define MTILES  ((N_NODES + 63) / 64)     // 782
#define NBUCK   ((N_NODES + 255) / 256)   // 196 buckets of 256 nodes
#define EPB     4096                       // edges per csr block
#define NBIN    ((ETOT + EPB - 1) / EPB)   // 208

// ---------------- workspace layout (bytes) ----------------
#define OFF_XL      ((size_t)0)                 // bf16 [N][128] = 12.8MB
#define OFF_EBUF    ((size_t)12800000)          // u32 [ETOT] = 3.4MB
#define OFF_XR      ((size_t)25600000)          // f32  [N][128] = 25.6MB
#define OFF_ROWPTR  ((size_t)51200000)          // (N+1)*4
#define OFF_BT      ((size_t)51400064)          // Bt bf16-pairs 64KB
#define OFF_SRC     ((size_t)51800064)          // ETOT*4 = 3.4MB
#define OFF_GCNT    ((size_t)55200064)
#define OFF_BSTART  ((size_t)55201088)
#define OFF_GCUR    ((size_t)55202112)

typedef float f32x4 __attribute__((ext_vector_type(4)));
typedef short s16x8 __attribute__((ext_vector_type(8)));

__device__ __forceinline__ unsigned f2bf(float f) {   // RNE f32->bf16 bits
    unsigned u = __float_as_uint(f);
    return (u + 0x7fffu + ((u >> 16) & 1u)) >> 16;
}
__device__ __forceinline__ float bflo(unsigned u) { return __uint_as_float(u << 16); }
__device__ __forceinline__ float bfhi(unsigned u) { return __uint_as_float(u & 0xffff0000u); }

__device__ __forceinline__ int SWZ(int row, int byteoff) {
    return row * 256 + (byteoff ^ ((row & 7) << 4));
}

// ============ W conversion + gcnt zero ============
__global__ __launch_bounds__(256) void wconv_kernel(
    const float* __restrict__ Wl, const float* __restrict__ Wr,
    unsigned* __restrict__ btg, int* __restrict__ gcnt)
{
    const int g = blockIdx.x * 256 + threadIdx.x;
    if (g < NBUCK) gcnt[g] = 0;
    if (g >= 256 * 64) return;
    const int n = g >> 6, kk = g & 63;
    const float* W = (n < 128) ? Wl : Wr;
    const int nc = n & 127;
    const float a = W[(size_t)(2 * kk) * 128 + nc];
    const float b = W[(size_t)(2 * kk + 1) * 128 + nc];
    btg[g] = f2bf(a) | (f2bf(b) << 16);
}

// ============ MFMA GEMM: x[N,128](f32->bf16) @ Bt -> xl(bf16), xr(f32) ============
__global__ __launch_bounds__(256) void gemm_kernel(
    const float* __restrict__ x, const unsigned* __restrict__ btg,
    unsigned* __restrict__ xl_bf, float* __restrict__ xr)
{
    __shared__ __align__(16) unsigned char Al[64 * 256];
    __shared__ __align__(16) unsigned char Bl[64 * 256];

    const int t  = threadIdx.x;
    const int nt = blockIdx.x / MTILES;
    const int mt = blockIdx.x % MTILES;
    const int mbase = mt * 64;
    const int nbase = nt * 64;

    {
        const int r = t >> 2, q = t & 3;
        int gm = mbase + r;
        gm = (gm < N_NODES) ? gm : (N_NODES - 1);
        const float* xrow = x + (size_t)gm * IN_CH + q * 32;
#pragma unroll
        for (int i = 0; i < 8; ++i) {
            const float4 xv = *(const float4*)(xrow + i * 4);
            uint2 p;
            p.x = f2bf(xv.x) | (f2bf(xv.y) << 16);
            p.y = f2bf(xv.z) | (f2bf(xv.w) << 16);
            *(uint2*)(Al + SWZ(r, q * 64 + i * 8)) = p;
        }
    }
    {
        const int r = t >> 2, q = t & 3;
        const unsigned* brow = btg + (size_t)(nbase + r) * 64 + q * 16;
#pragma unroll
        for (int i = 0; i < 4; ++i) {
            const uint4 v = *(const uint4*)(brow + i * 4);
            *(uint4*)(Bl + SWZ(r, q * 64 + i * 16)) = v;
        }
    }
    __syncthreads();

    const int l  = t & 63;
    const int wv = t >> 6;

    f32x4 acc[4];
#pragma unroll
    for (int n = 0; n < 4; ++n) acc[n] = (f32x4){0.f, 0.f, 0.f, 0.f};

    s16x8 af[4];
#pragma unroll
    for (int ks = 0; ks < 4; ++ks)
        af[ks] = *(const s16x8*)(Al + SWZ(wv * 16 + (l & 15), ks * 64 + (l >> 4) * 16));

#pragma unroll
    for (int nsub = 0; nsub < 4; ++nsub) {
#pragma unroll
        for (int ks = 0; ks < 4; ++ks) {
            const s16x8 bfr = *(const s16x8*)(Bl + SWZ(nsub * 16 + (l & 15), ks * 64 + (l >> 4) * 16));
            acc[nsub] = __builtin_amdgcn_mfma_f32_16x16x32_bf16(af[ks], bfr, acc[nsub], 0, 0, 0);
        }
    }

    if (nt < 2) {
#pragma unroll
        for (int nsub = 0; nsub < 4; ++nsub) {
            const int n = nt * 64 + nsub * 16 + (l & 15);
#pragma unroll
            for (int reg = 0; reg < 4; ++reg) {
                const float v  = acc[nsub][reg];
                const float vp = __shfl_xor(v, 1);
                const int row = mbase + wv * 16 + (l >> 4) * 4 + reg;
                if (((l & 1) == 0) && row < N_NODES)
                    xl_bf[(size_t)row * 64 + (n >> 1)] = f2bf(v) | (f2bf(vp) << 16);
            }
        }
    } else {
#pragma unroll
        for (int nsub = 0; nsub < 4; ++nsub) {
            const int cx = (nt - 2) * 64 + nsub * 16 + (l & 15);
#pragma unroll
            for (int reg = 0; reg < 4; ++reg) {
                const int row = mbase + wv * 16 + (l >> 4) * 4 + reg;
                if (row < N_NODES)
                    xr[(size_t)row * TOT_CH + cx] = acc[nsub][reg];
            }
        }
    }
}

// ================= fused CSR build (cooperative, 4 phases) =================
__global__ __launch_bounds__(512) void csr_kernel(
    const int* __restrict__ ei, unsigned* __restrict__ ebuf,
    int* __restrict__ gcnt, int* __restrict__ bstart, int* __restrict__ gcur,
    int* __restrict__ rowptr, int* __restrict__ ssrc)
{
    __shared__ int sh1[256];
    __shared__ int sh2[256];
    __shared__ int wsum[8];
    const int tid = threadIdx.x;
    const int bid = blockIdx.x;

    // ---- phase 1: per-block bucket histogram of my edge slice ----
    if (tid < 256) sh1[tid] = 0;
    __syncthreads();
    int sv[8], dv[8];
    const int base = bid * EPB;
#pragma unroll
    for (int u = 0; u < 8; ++u) {
        const int e = base + u * 512 + tid;
        int s32 = 0, d32 = -1;
        if (e < ETOT) {
            if (e < NEDGE) { s32 = ei[e]; d32 = ei[NEDGE + e]; }
            else           { s32 = d32 = e - NEDGE; }
            atomicAdd(&sh1[d32 >> 8], 1);
        }
        sv[u] = s32; dv[u] = d32;
    }
    __syncthreads();
    if (tid < NBUCK) { const int v = sh1[tid]; if (v) atomicAdd(&gcnt[tid], v); }
    cg::this_grid().sync();

    // ---- phase 2: block 0 scans bucket counts -> bstart, gcur ----
    if (bid == 0) {
        const int lane = tid & 63, wid = tid >> 6;
        int v = 0, s = 0;
        if (tid < 256) {
            v = (tid < NBUCK) ? gcnt[tid] : 0;
            s = v;
#pragma unroll
            for (int off = 1; off < 64; off <<= 1) {
                int t = __shfl_up(s, off);
                if (lane >= off) s += t;
            }
            if (lane == 63) wsum[wid] = s;
        }
        __syncthreads();
        if (tid == 0) {
            int acc = 0;
#pragma unroll
            for (int w = 0; w < 4; ++w) { int t = wsum[w]; wsum[w] = acc; acc += t; }
        }
        __syncthreads();
        if (tid < NBUCK) {
            const int e = wsum[wid] + s - v;
            bstart[tid] = e;
            gcur[tid] = e;
        }
        if (tid == 0) rowptr[N_NODES] = ETOT;
    }
    cg::this_grid().sync();

    // ---- phase 3: scatter packed (src | dlow<<16) into bucket-ordered ebuf ----
    // sh1 still holds this block's per-bucket counts from phase 1.
    if (tid < 256) sh2[tid] = 0;
    __syncthreads();
    if (tid < NBUCK) { const int v = sh1[tid]; sh2[tid] = v ? atomicAdd(&gcur[tid], v) : 0; }
    __syncthreads();
    if (tid < 256) sh1[tid] = 0;
    __syncthreads();
#pragma unroll
    for (int u = 0; u < 8; ++u) {
        const int d32 = dv[u];
        if (d32 >= 0) {
            const int b = d32 >> 8;
            const int p = sh2[b] + atomicAdd(&sh1[b], 1);
            ebuf[p] = (unsigned)sv[u] | ((unsigned)(d32 & 255) << 16);
        }
    }
    cg::this_grid().sync();

    // ---- phase 4: per-bucket place (rowptr + ssrc), LDS atomics only ----
    if (bid < NBUCK) {
        const int estart = bstart[bid];
        const int ecnt   = gcnt[bid];
        if (tid < 256) sh1[tid] = 0;
        __syncthreads();
        for (int k = tid; k < ecnt; k += 512)
            atomicAdd(&sh1[(ebuf[estart + k] >> 16) & 255], 1);
        __syncthreads();
        const int lane = tid & 63, wid = tid >> 6;
        int v = 0, s = 0;
        if (tid < 256) {
            v = sh1[tid]; s = v;
#pragma unroll
            for (int off = 1; off < 64; off <<= 1) {
                int t = __shfl_up(s, off);
                if (lane >= off) s += t;
            }
            if (lane == 63) wsum[wid] = s;
        }
        __syncthreads();
        if (tid == 0) {
            int acc = 0;
#pragma unroll
            for (int w = 0; w < 4; ++w) { int t = wsum[w]; wsum[w] = acc; acc += t; }
        }
        __syncthreads();
        if (tid < 256) {
            const int gpos = estart + wsum[wid] + s - v;
            const int node = (bid << 8) + tid;
            if (node < N_NODES) rowptr[node] = gpos;
            sh2[tid] = gpos;
        }
        __syncthreads();
        for (int k = tid; k < ecnt; k += 512) {
            const unsigned ed = ebuf[estart + k];
            const int p = atomicAdd(&sh2[(ed >> 16) & 255], 1);
            ssrc[p] = (int)(ed & 0xffffu);
        }
    }
}

// ================= fused attention + aggregate: one wave per dst node =========
#define RED4(a, b, cc, d) do { \
        a += __shfl_xor(a, 1); b += __shfl_xor(b, 1); cc += __shfl_xor(cc, 1); d += __shfl_xor(d, 1); \
        a += __shfl_xor(a, 2); b += __shfl_xor(b, 2); cc += __shfl_xor(cc, 2); d += __shfl_xor(d, 2); \
        a += __shfl_xor(a, 4); b += __shfl_xor(b, 4); cc += __shfl_xor(cc, 4); d += __shfl_xor(d, 4); \
        a += __shfl_xor(a, 8); b += __shfl_xor(b, 8); cc += __shfl_xor(cc, 8); d += __shfl_xor(d, 8); } while(0)

template<bool MASKED>
__device__ __forceinline__ void batch8(
    int k, int kseg, int kend, int idx, int lane,
    const unsigned* __restrict__ xl_bf,
    float xr2x, float xr2y, float a6x, float a4x, float a6y, float a4y,
    float& m, float& den, float& b0, float& b1)
{
    const int t = k - kseg;
    const int r = kend - k;     // valid edges (>=1); full batch when r>=8
#define IDXN(n) __builtin_amdgcn_readfirstlane(__shfl(idx, MASKED ? (t + min(n, r - 1)) : (t + n)))
    const int j0 = IDXN(0); const int j1 = IDXN(1);
    const int j2 = IDXN(2); const int j3 = IDXN(3);
    const int j4 = IDXN(4); const int j5 = IDXN(5);
    const int j6 = IDXN(6); const int j7 = IDXN(7);
#undef IDXN
    const unsigned u0 = xl_bf[(size_t)j0 * 64 + lane];
    const unsigned u1 = xl_bf[(size_t)j1 * 64 + lane];
    const unsigned u2 = xl_bf[(size_t)j2 * 64 + lane];
    const unsigned u3 = xl_bf[(size_t)j3 * 64 + lane];
    const unsigned u4 = xl_bf[(size_t)j4 * 64 + lane];
    const unsigned u5 = xl_bf[(size_t)j5 * 64 + lane];
    const unsigned u6 = xl_bf[(size_t)j6 * 64 + lane];
    const unsigned u7 = xl_bf[(size_t)j7 * 64 + lane];
#define SCORE(n) \
    const float t0_##n = bflo(u##n) + xr2x; \
    const float t1_##n = bfhi(u##n) + xr2y; \
    float s##n = fmaf(a6x, t0_##n, fmaf(a4x, fabsf(t0_##n), \
                 fmaf(a6y, t1_##n, a4y * fabsf(t1_##n))));
    SCORE(0); SCORE(1); SCORE(2); SCORE(3);
    SCORE(4); SCORE(5); SCORE(6); SCORE(7);
#undef SCORE
    RED4(s0, s1, s2, s3);
    RED4(s4, s5, s6, s7);
    if (MASKED) {
        s1 = (1 < r) ? s1 : -1e30f;
        s2 = (2 < r) ? s2 : -1e30f;
        s3 = (3 < r) ? s3 : -1e30f;
        s4 = (4 < r) ? s4 : -1e30f;
        s5 = (5 < r) ? s5 : -1e30f;
        s6 = (6 < r) ? s6 : -1e30f;
        s7 = (7 < r) ? s7 : -1e30f;
    }
    const float mx = fmaxf(fmaxf(fmaxf(s0, s1), fmaxf(s2, s3)),
                           fmaxf(fmaxf(s4, s5), fmaxf(s6, s7)));
    if (__any(mx > m)) {
        const float mn = fmaxf(mx, m);
        const float corr = (m == -INFINITY) ? 0.f : __expf(m - mn);
        den *= corr; b0 *= corr; b1 *= corr;
        m = mn;
    }
    const float p0 = __expf(s0 - m), p1 = __expf(s1 - m);
    const float p2 = __expf(s2 - m), p3 = __expf(s3 - m);
    const float p4 = __expf(s4 - m), p5 = __expf(s5 - m);
    const float p6 = __expf(s6 - m), p7 = __expf(s7 - m);
    den += ((p0 + p1) + (p2 + p3)) + ((p4 + p5) + (p6 + p7));
    b0 = fmaf(p0, t0_0, fmaf(p1, t0_1, fmaf(p2, t0_2, fmaf(p3, t0_3,
         fmaf(p4, t0_4, fmaf(p5, t0_5, fmaf(p6, t0_6, fmaf(p7, t0_7, b0))))))));
    b1 = fmaf(p0, t1_0, fmaf(p1, t1_1, fmaf(p2, t1_2, fmaf(p3, t1_3,
         fmaf(p4, t1_4, fmaf(p5, t1_5, fmaf(p6, t1_6, fmaf(p7, t1_7, b1))))))));
}

__global__ __launch_bounds__(256) void gat_kernel(
    const unsigned* __restrict__ xl_bf, const float* __restrict__ xr,
    const int* __restrict__ rowptr, const int* __restrict__ srcs,
    const float* __restrict__ att, const float* __restrict__ bias,
    float* __restrict__ out)
{
    const int lane = threadIdx.x & 63;
    const int i = blockIdx.x * 4 + (threadIdx.x >> 6);
    if (i >= N_NODES) return;
    const int c = lane * 2;                       // 2 channels per lane; head = lane>>4
    const float2 att2 = *(const float2*)(att + c);
    const float2 xr2  = *(const float2*)(xr + (size_t)i * TOT_CH + c);
    const float a6x = 0.6f * att2.x, a4x = 0.4f * att2.x;
    const float a6y = 0.6f * att2.y, a4y = 0.4f * att2.y;
    const int k0 = rowptr[i], k1 = rowptr[i + 1];

    float m = -INFINITY, den = 0.f, b0 = 0.f, b1 = 0.f;

    for (int kseg = k0; kseg < k1; kseg += 64) {
        const int kend = min(kseg + 64, k1);
        const int idx = srcs[min(kseg + lane, k1 - 1)];   // one coalesced load covers <=64 edges
        int k = kseg;
        for (; k + 8 <= kend; k += 8)
            batch8<false>(k, kseg, kend, idx, lane, xl_bf,
                          xr2.x, xr2.y, a6x, a4x, a6y, a4y, m, den, b0, b1);
        if (k < kend)
            batch8<true>(k, kseg, kend, idx, lane, xl_bf,
                         xr2.x, xr2.y, a6x, a4x, a6y, a4y, m, den, b0, b1);
    }

    const float inv = 1.f / den;
    const float2 bb = *(const float2*)(bias + c);
    float2 o;
    o.x = fmaf(b0, inv, bb.x - xr2.x);
    o.y = fmaf(b1, inv, bb.y - xr2.y);
    *(float2*)(out + (size_t)i * TOT_CH + c) = o;
}

// ================= launch =================
extern "C" void kernel_launch(void* const* d_in, const int* in_sizes, int n_in,
                              void* d_out, int out_size, void* d_ws, size_t ws_size,
                              hipStream_t stream) {
    const float* x    = (const float*)d_in[0];
    const int*   ei   = (const int*)d_in[1];
    const float* Wl   = (const float*)d_in[2];
    const float* Wr   = (const float*)d_in[3];
    const float* att  = (const float*)d_in[4];
    const float* bias = (const float*)d_in[5];
    float* out = (float*)d_out;
    char*  ws  = (char*)d_ws;

    unsigned* xl_bf = (unsigned*)(ws + OFF_XL);
    unsigned* ebuf  = (unsigned*)(ws + OFF_EBUF);
    float*    xr    = (float*)(ws + OFF_XR);
    int*   rowptr = (int*)(ws + OFF_ROWPTR);
    unsigned* btg = (unsigned*)(ws + OFF_BT);
    int*   ssrc   = (int*)(ws + OFF_SRC);
    int*   gcnt   = (int*)(ws + OFF_GCNT);
    int*   bstart = (int*)(ws + OFF_BSTART);
    int*   gcur   = (int*)(ws + OFF_GCUR);

    hipLaunchKernelGGL(wconv_kernel, dim3(64), dim3(256), 0, stream, Wl, Wr, btg, gcnt);
    hipLaunchKernelGGL(gemm_kernel, dim3(MTILES * 4), dim3(256), 0, stream,
                       x, btg, xl_bf, xr);

    void* csr_args[] = { (void*)&ei, (void*)&ebuf, (void*)&gcnt, (void*)&bstart,
                         (void*)&gcur, (void*)&rowptr, (void*)&ssrc };
    hipLaunchCooperativeKernel((void*)csr_kernel, dim3(NBIN), dim3(512),
                               csr_args, 0, stream);

    hipLaunchKernelGGL(gat_kernel, dim3((N_NODES + 3) / 4), dim3(256), 0, stream,
                       xl_bf, xr, rowptr, ssrc, att, bias, out);
}

// Round 10
// 115.914 us; speedup vs baseline: 1.6981x; 1.6981x over previous
//
#include <hip/hip_runtime.h>
#include <math.h>

#define N_NODES 50000
#define IN_CH   128
#define TOT_CH  128          // HEADS*OUT_CH
#define NEDGE   800000
#define ETOT    (NEDGE + N_NODES)
#define MTILES  ((N_NODES + 63) / 64)     // 782
#define NBUCK   ((N_NODES + 255) / 256)   // 196 buckets of 256 nodes
#define EPB     4096                       // edges per binning block
#define NBIN    ((ETOT + EPB - 1) / EPB)   // 208

// ---------------- workspace layout (bytes) ----------------
#define OFF_XL      ((size_t)0)                 // bf16 [N][128] = 12.8MB
#define OFF_EBUF    ((size_t)12800000)          // u32 [ETOT] = 3.4MB
#define OFF_XR      ((size_t)25600000)          // bf16 [N][128] = 12.8MB
#define OFF_ROWPTR  ((size_t)51200000)          // (N+1)*4
#define OFF_BT      ((size_t)51400064)          // Bt bf16-pairs 64KB
#define OFF_SRC     ((size_t)51800064)          // ETOT*4 = 3.4MB
#define OFF_GCNT    ((size_t)55200064)
#define OFF_BSTART  ((size_t)55201088)
#define OFF_GCUR    ((size_t)55202112)

typedef float f32x4 __attribute__((ext_vector_type(4)));
typedef short s16x8 __attribute__((ext_vector_type(8)));

__device__ __forceinline__ unsigned f2bf(float f) {   // RNE f32->bf16 bits
    unsigned u = __float_as_uint(f);
    return (u + 0x7fffu + ((u >> 16) & 1u)) >> 16;
}
__device__ __forceinline__ float bflo(unsigned u) { return __uint_as_float(u << 16); }
__device__ __forceinline__ float bfhi(unsigned u) { return __uint_as_float(u & 0xffff0000u); }

__device__ __forceinline__ int SWZ(int row, int byteoff) {
    return row * 256 + (byteoff ^ ((row & 7) << 4));
}

// ============ W conversion + gcnt zero ============
__global__ __launch_bounds__(256) void wconv_kernel(
    const float* __restrict__ Wl, const float* __restrict__ Wr,
    unsigned* __restrict__ btg, int* __restrict__ gcnt)
{
    const int g = blockIdx.x * 256 + threadIdx.x;
    if (g < NBUCK) gcnt[g] = 0;
    if (g >= 256 * 64) return;
    const int n = g >> 6, kk = g & 63;
    const float* W = (n < 128) ? Wl : Wr;
    const int nc = n & 127;
    const float a = W[(size_t)(2 * kk) * 128 + nc];
    const float b = W[(size_t)(2 * kk + 1) * 128 + nc];
    btg[g] = f2bf(a) | (f2bf(b) << 16);
}

// ============ MFMA GEMM: x[N,128](f32->bf16) @ Bt -> xl(bf16), xr(bf16) ============
__global__ __launch_bounds__(256) void gemm_kernel(
    const float* __restrict__ x, const unsigned* __restrict__ btg,
    unsigned* __restrict__ xl_bf, unsigned* __restrict__ xr_bf)
{
    __shared__ __align__(16) unsigned char Al[64 * 256];
    __shared__ __align__(16) unsigned char Bl[64 * 256];

    const int t  = threadIdx.x;
    const int nt = blockIdx.x / MTILES;
    const int mt = blockIdx.x % MTILES;
    const int mbase = mt * 64;
    const int nbase = nt * 64;

    {
        const int r = t >> 2, q = t & 3;
        int gm = mbase + r;
        gm = (gm < N_NODES) ? gm : (N_NODES - 1);
        const float* xrow = x + (size_t)gm * IN_CH + q * 32;
#pragma unroll
        for (int i = 0; i < 8; ++i) {
            const float4 xv = *(const float4*)(xrow + i * 4);
            uint2 p;
            p.x = f2bf(xv.x) | (f2bf(xv.y) << 16);
            p.y = f2bf(xv.z) | (f2bf(xv.w) << 16);
            *(uint2*)(Al + SWZ(r, q * 64 + i * 8)) = p;
        }
    }
    {
        const int r = t >> 2, q = t & 3;
        const unsigned* brow = btg + (size_t)(nbase + r) * 64 + q * 16;
#pragma unroll
        for (int i = 0; i < 4; ++i) {
            const uint4 v = *(const uint4*)(brow + i * 4);
            *(uint4*)(Bl + SWZ(r, q * 64 + i * 16)) = v;
        }
    }
    __syncthreads();

    const int l  = t & 63;
    const int wv = t >> 6;

    f32x4 acc[4];
#pragma unroll
    for (int n = 0; n < 4; ++n) acc[n] = (f32x4){0.f, 0.f, 0.f, 0.f};

    s16x8 af[4];
#pragma unroll
    for (int ks = 0; ks < 4; ++ks)
        af[ks] = *(const s16x8*)(Al + SWZ(wv * 16 + (l & 15), ks * 64 + (l >> 4) * 16));

#pragma unroll
    for (int nsub = 0; nsub < 4; ++nsub) {
#pragma unroll
        for (int ks = 0; ks < 4; ++ks) {
            const s16x8 bfr = *(const s16x8*)(Bl + SWZ(nsub * 16 + (l & 15), ks * 64 + (l >> 4) * 16));
            acc[nsub] = __builtin_amdgcn_mfma_f32_16x16x32_bf16(af[ks], bfr, acc[nsub], 0, 0, 0);
        }
    }

    // epilogue: C/D map col=lane&15, row=(lane>>4)*4+reg; both outputs bf16-paired
    unsigned* dstbuf = (nt < 2) ? xl_bf : xr_bf;
    const int ncol0 = (nt & 1) * 64;
#pragma unroll
    for (int nsub = 0; nsub < 4; ++nsub) {
        const int n = ncol0 + nsub * 16 + (l & 15);
#pragma unroll
        for (int reg = 0; reg < 4; ++reg) {
            const float v  = acc[nsub][reg];
            const float vp = __shfl_xor(v, 1);
            const int row = mbase + wv * 16 + (l >> 4) * 4 + reg;
            if (((l & 1) == 0) && row < N_NODES)
                dstbuf[(size_t)row * 64 + (n >> 1)] = f2bf(v) | (f2bf(vp) << 16);
        }
    }
}

// ================= CSR build via bucketed counting sort =================
__global__ __launch_bounds__(256) void binA_kernel(
    const int* __restrict__ ei, int* __restrict__ gcnt)
{
    __shared__ int lcnt[NBUCK];
    for (int i = threadIdx.x; i < NBUCK; i += 256) lcnt[i] = 0;
    __syncthreads();
    const int base = blockIdx.x * EPB;
#pragma unroll
    for (int u = 0; u < 16; ++u) {
        const int e = base + u * 256 + threadIdx.x;
        if (e < ETOT) {
            const int dst = (e < NEDGE) ? ei[NEDGE + e] : (e - NEDGE);
            atomicAdd(&lcnt[dst >> 8], 1);
        }
    }
    __syncthreads();
    for (int i = threadIdx.x; i < NBUCK; i += 256) {
        const int v = lcnt[i];
        if (v) atomicAdd(&gcnt[i], v);
    }
}

__global__ __launch_bounds__(256) void scanB_kernel(
    const int* __restrict__ gcnt, int* __restrict__ bstart,
    int* __restrict__ gcursor, int* __restrict__ rowptr)
{
    __shared__ int wsum[4];
    const int tid = threadIdx.x, lane = tid & 63, wid = tid >> 6;
    const int v = (tid < NBUCK) ? gcnt[tid] : 0;
    int s = v;
#pragma unroll
    for (int off = 1; off < 64; off <<= 1) {
        int t = __shfl_up(s, off);
        if (lane >= off) s += t;
    }
    if (lane == 63) wsum[wid] = s;
    __syncthreads();
    if (tid == 0) {
        int acc = 0;
#pragma unroll
        for (int w = 0; w < 4; ++w) { int t = wsum[w]; wsum[w] = acc; acc += t; }
    }
    __syncthreads();
    if (tid < NBUCK) {
        const int e = wsum[wid] + s - v;
        bstart[tid] = e;
        gcursor[tid] = e;
    }
    if (tid == 0) rowptr[N_NODES] = ETOT;
}

__global__ __launch_bounds__(256) void binscatter_kernel(
    const int* __restrict__ ei, int* __restrict__ gcursor, unsigned* __restrict__ ebuf)
{
    __shared__ int lcnt[NBUCK];
    __shared__ int lbase[NBUCK];
    for (int i = threadIdx.x; i < NBUCK; i += 256) lcnt[i] = 0;
    __syncthreads();
    const int base = blockIdx.x * EPB;
    int srcv[16], dstv[16];
#pragma unroll
    for (int u = 0; u < 16; ++u) {
        const int e = base + u * 256 + threadIdx.x;
        int s32 = 0, d32 = -1;
        if (e < ETOT) {
            if (e < NEDGE) { s32 = ei[e]; d32 = ei[NEDGE + e]; }
            else           { s32 = d32 = e - NEDGE; }
            atomicAdd(&lcnt[d32 >> 8], 1);
        }
        srcv[u] = s32; dstv[u] = d32;
    }
    __syncthreads();
    for (int i = threadIdx.x; i < NBUCK; i += 256) {
        const int v = lcnt[i];
        lbase[i] = v ? atomicAdd(&gcursor[i], v) : 0;
    }
    __syncthreads();
    for (int i = threadIdx.x; i < NBUCK; i += 256) lcnt[i] = 0;
    __syncthreads();
#pragma unroll
    for (int u = 0; u < 16; ++u) {
        const int d32 = dstv[u];
        if (d32 >= 0) {
            const int b = d32 >> 8;
            const int p = lbase[b] + atomicAdd(&lcnt[b], 1);
            ebuf[p] = (unsigned)srcv[u] | ((unsigned)(d32 & 255) << 16);   // src<65536
        }
    }
}

__global__ __launch_bounds__(512) void place_kernel(
    const unsigned* __restrict__ ebuf, const int* __restrict__ gcnt,
    const int* __restrict__ bstart, int* __restrict__ rowptr, int* __restrict__ ssrc)
{
    __shared__ int lcnt[256];
    __shared__ int lcur[256];
    __shared__ int wsum[4];
    const int b = blockIdx.x;
    const int node0 = b << 8;
    const int estart = bstart[b];
    const int ecnt = gcnt[b];
    const int tid = threadIdx.x, lane = tid & 63, wid = tid >> 6;
    if (tid < 256) lcnt[tid] = 0;
    __syncthreads();
    for (int k = tid; k < ecnt; k += 512)
        atomicAdd(&lcnt[(ebuf[estart + k] >> 16) & 255], 1);
    __syncthreads();
    int v = 0, s = 0;
    if (tid < 256) {
        v = lcnt[tid]; s = v;
#pragma unroll
        for (int off = 1; off < 64; off <<= 1) {
            int t = __shfl_up(s, off);
            if (lane >= off) s += t;
        }
        if (lane == 63) wsum[wid] = s;
    }
    __syncthreads();
    if (tid == 0) {
        int acc = 0;
#pragma unroll
        for (int w = 0; w < 4; ++w) { int t = wsum[w]; wsum[w] = acc; acc += t; }
    }
    __syncthreads();
    if (tid < 256) {
        const int gpos = estart + wsum[wid] + s - v;
        const int node = node0 + tid;
        if (node < N_NODES) rowptr[node] = gpos;
        lcur[tid] = gpos;
    }
    __syncthreads();
    for (int k = tid; k < ecnt; k += 512) {
        const unsigned ed = ebuf[estart + k];
        const int p = atomicAdd(&lcur[(ed >> 16) & 255], 1);
        ssrc[p] = (int)(ed & 0xffffu);
    }
}

// ================= fused attention + aggregate: one wave per dst node =========
__global__ __launch_bounds__(256) void gat_kernel(
    const unsigned* __restrict__ xl_bf, const unsigned* __restrict__ xr_bf,
    const int* __restrict__ rowptr, const int* __restrict__ srcs,
    const float* __restrict__ att, const float* __restrict__ bias,
    float* __restrict__ out)
{
    const int lane = threadIdx.x & 63;
    const int i = blockIdx.x * 4 + (threadIdx.x >> 6);
    if (i >= N_NODES) return;
    const int c = lane * 2;
    const float2 att2 = *(const float2*)(att + c);
    const unsigned ur = xr_bf[(size_t)i * 64 + lane];
    const float xr2x = bflo(ur), xr2y = bfhi(ur);
    const float a6x = 0.6f * att2.x, a4x = 0.4f * att2.x;
    const float a6y = 0.6f * att2.y, a4y = 0.4f * att2.y;
    const int k0 = rowptr[i], k1 = rowptr[i + 1];

    float m = -INFINITY, den = 0.f, b0 = 0.f, b1 = 0.f;
    int k = k0;

#define LOADU(n, kk) \
    const int j##n = __builtin_amdgcn_readfirstlane(srcs[kk]); \
    const unsigned u##n = *(xl_bf + (size_t)j##n * 64 + lane);

#define SCORE(n) \
    const float t0_##n = bflo(u##n) + xr2x; \
    const float t1_##n = bfhi(u##n) + xr2y; \
    float s##n = fmaf(a6x, t0_##n, fmaf(a4x, fabsf(t0_##n), \
                 fmaf(a6y, t1_##n, a4y * fabsf(t1_##n))));

#define RED4(a, b, cc, d) do { \
        a += __shfl_xor(a, 1); b += __shfl_xor(b, 1); cc += __shfl_xor(cc, 1); d += __shfl_xor(d, 1); \
        a += __shfl_xor(a, 2); b += __shfl_xor(b, 2); cc += __shfl_xor(cc, 2); d += __shfl_xor(d, 2); \
        a += __shfl_xor(a, 4); b += __shfl_xor(b, 4); cc += __shfl_xor(cc, 4); d += __shfl_xor(d, 4); \
        a += __shfl_xor(a, 8); b += __shfl_xor(b, 8); cc += __shfl_xor(cc, 8); d += __shfl_xor(d, 8); } while(0)

    for (; k + 8 <= k1; k += 8) {
        LOADU(0, k + 0); LOADU(1, k + 1); LOADU(2, k + 2); LOADU(3, k + 3);
        LOADU(4, k + 4); LOADU(5, k + 5); LOADU(6, k + 6); LOADU(7, k + 7);
        SCORE(0); SCORE(1); SCORE(2); SCORE(3);
        SCORE(4); SCORE(5); SCORE(6); SCORE(7);
        RED4(s0, s1, s2, s3);
        RED4(s4, s5, s6, s7);
        const float mx = fmaxf(fmaxf(fmaxf(s0, s1), fmaxf(s2, s3)),
                               fmaxf(fmaxf(s4, s5), fmaxf(s6, s7)));
        if (__any(mx > m)) {
            const float mn = fmaxf(mx, m);
            const float corr = (m == -INFINITY) ? 0.f : __expf(m - mn);
            den *= corr; b0 *= corr; b1 *= corr;
            m = mn;
        }
        const float p0 = __expf(s0 - m), p1 = __expf(s1 - m);
        const float p2 = __expf(s2 - m), p3 = __expf(s3 - m);
        const float p4 = __expf(s4 - m), p5 = __expf(s5 - m);
        const float p6 = __expf(s6 - m), p7 = __expf(s7 - m);
        den += ((p0 + p1) + (p2 + p3)) + ((p4 + p5) + (p6 + p7));
        b0 = fmaf(p0, t0_0, fmaf(p1, t0_1, fmaf(p2, t0_2, fmaf(p3, t0_3,
             fmaf(p4, t0_4, fmaf(p5, t0_5, fmaf(p6, t0_6, fmaf(p7, t0_7, b0))))))));
        b1 = fmaf(p0, t1_0, fmaf(p1, t1_1, fmaf(p2, t1_2, fmaf(p3, t1_3,
             fmaf(p4, t1_4, fmaf(p5, t1_5, fmaf(p6, t1_6, fmaf(p7, t1_7, b1))))))));
    }
    if (k + 4 <= k1) {
        LOADU(0, k + 0); LOADU(1, k + 1); LOADU(2, k + 2); LOADU(3, k + 3);
        SCORE(0); SCORE(1); SCORE(2); SCORE(3);
        RED4(s0, s1, s2, s3);
        const float mx = fmaxf(fmaxf(s0, s1), fmaxf(s2, s3));
        if (__any(mx > m)) {
            const float mn = fmaxf(mx, m);
            const float corr = (m == -INFINITY) ? 0.f : __expf(m - mn);
            den *= corr; b0 *= corr; b1 *= corr;
            m = mn;
        }
        const float p0 = __expf(s0 - m), p1 = __expf(s1 - m);
        const float p2 = __expf(s2 - m), p3 = __expf(s3 - m);
        den += (p0 + p1) + (p2 + p3);
        b0 = fmaf(p0, t0_0, fmaf(p1, t0_1, fmaf(p2, t0_2, fmaf(p3, t0_3, b0))));
        b1 = fmaf(p0, t1_0, fmaf(p1, t1_1, fmaf(p2, t1_2, fmaf(p3, t1_3, b1))));
        k += 4;
    }
    for (; k < k1; ++k) {
        LOADU(9, k);
        SCORE(9);
        s9 += __shfl_xor(s9, 1);
        s9 += __shfl_xor(s9, 2);
        s9 += __shfl_xor(s9, 4);
        s9 += __shfl_xor(s9, 8);
        if (__any(s9 > m)) {
            const float mn = fmaxf(s9, m);
            const float corr = (m == -INFINITY) ? 0.f : __expf(m - mn);
            den *= corr; b0 *= corr; b1 *= corr;
            m = mn;
        }
        const float p = __expf(s9 - m);
        den += p;
        b0 = fmaf(p, t0_9, b0);
        b1 = fmaf(p, t1_9, b1);
    }
    const float inv = 1.f / den;
    const float2 bb = *(const float2*)(bias + c);
    float2 o;
    o.x = fmaf(b0, inv, bb.x - xr2x);
    o.y = fmaf(b1, inv, bb.y - xr2y);
    *(float2*)(out + (size_t)i * TOT_CH + c) = o;
}

// ================= launch =================
extern "C" void kernel_launch(void* const* d_in, const int* in_sizes, int n_in,
                              void* d_out, int out_size, void* d_ws, size_t ws_size,
                              hipStream_t stream) {
    const float* x    = (const float*)d_in[0];
    const int*   ei   = (const int*)d_in[1];
    const float* Wl   = (const float*)d_in[2];
    const float* Wr   = (const float*)d_in[3];
    const float* att  = (const float*)d_in[4];
    const float* bias = (const float*)d_in[5];
    float* out = (float*)d_out;
    char*  ws  = (char*)d_ws;

    unsigned* xl_bf = (unsigned*)(ws + OFF_XL);
    unsigned* ebuf  = (unsigned*)(ws + OFF_EBUF);
    unsigned* xr_bf = (unsigned*)(ws + OFF_XR);
    int*   rowptr = (int*)(ws + OFF_ROWPTR);
    unsigned* btg = (unsigned*)(ws + OFF_BT);
    int*   ssrc   = (int*)(ws + OFF_SRC);
    int*   gcnt   = (int*)(ws + OFF_GCNT);
    int*   bstart = (int*)(ws + OFF_BSTART);
    int*   gcur   = (int*)(ws + OFF_GCUR);

    hipLaunchKernelGGL(wconv_kernel, dim3(64), dim3(256), 0, stream, Wl, Wr, btg, gcnt);
    hipLaunchKernelGGL(gemm_kernel, dim3(MTILES * 4), dim3(256), 0, stream,
                       x, btg, xl_bf, xr_bf);
    hipLaunchKernelGGL(binA_kernel, dim3(NBIN), dim3(256), 0, stream, ei, gcnt);
    hipLaunchKernelGGL(scanB_kernel, dim3(1), dim3(256), 0, stream, gcnt, bstart, gcur, rowptr);
    hipLaunchKernelGGL(binscatter_kernel, dim3(NBIN), dim3(256), 0, stream, ei, gcur, ebuf);
    hipLaunchKernelGGL(place_kernel, dim3(NBUCK), dim3(512), 0, stream,
                       ebuf, gcnt, bstart, rowptr, ssrc);
    hipLaunchKernelGGL(gat_kernel, dim3((N_NODES + 3) / 4), dim3(256), 0, stream,
                       xl_bf, xr_bf, rowptr, ssrc, att, bias, out);
}

// Round 11
// 113.203 us; speedup vs baseline: 1.7388x; 1.0240x over previous
//
#include <hip/hip_runtime.h>
#include <math.h>

#define N_NODES 50000
#define IN_CH   128
#define TOT_CH  128          // HEADS*OUT_CH
#define NEDGE   800000
#define ETOT    (NEDGE + N_NODES)
#define MTILES  ((N_NODES + 63) / 64)     // 782
#define NBUCK   ((N_NODES + 255) / 256)   // 196 buckets of 256 nodes
#define EPB     4096                       // edges per binning block
#define NBIN    ((ETOT + EPB - 1) / EPB)   // 208

// ---------------- workspace layout (bytes) ----------------
#define OFF_XL      ((size_t)0)                 // bf16 [N][128] = 12.8MB
#define OFF_EBUF    ((size_t)12800000)          // u32 [ETOT] = 3.4MB
#define OFF_XR      ((size_t)25600000)          // bf16 [N][128] = 12.8MB
#define OFF_ROWPTR  ((size_t)51200000)          // (N+1)*4
#define OFF_BT      ((size_t)51400064)          // Bt bf16-pairs 64KB
#define OFF_SRC     ((size_t)51800064)          // ETOT*4 = 3.4MB
#define OFF_GCNT    ((size_t)55200064)
#define OFF_BSTART  ((size_t)55201088)
#define OFF_BCNT    ((size_t)55203136)          // int [NBIN][256] = 213KB

typedef float f32x4 __attribute__((ext_vector_type(4)));
typedef short s16x8 __attribute__((ext_vector_type(8)));

__device__ __forceinline__ unsigned f2bf(float f) {   // RNE f32->bf16 bits
    unsigned u = __float_as_uint(f);
    return (u + 0x7fffu + ((u >> 16) & 1u)) >> 16;
}
__device__ __forceinline__ float bflo(unsigned u) { return __uint_as_float(u << 16); }
__device__ __forceinline__ float bfhi(unsigned u) { return __uint_as_float(u & 0xffff0000u); }

__device__ __forceinline__ int SWZ(int row, int byteoff) {
    return row * 256 + (byteoff ^ ((row & 7) << 4));
}

// ============ K1: binA (private per-block counts) || wconv ============
__global__ __launch_bounds__(256) void k1_kernel(
    const float* __restrict__ Wl, const float* __restrict__ Wr,
    unsigned* __restrict__ btg, const int* __restrict__ ei, int* __restrict__ bcnt)
{
    __shared__ int lcnt[256];
    const int bid = blockIdx.x;
    const int tid = threadIdx.x;
    if (bid < NBIN) {
        lcnt[tid] = 0;
        __syncthreads();
        const int base = bid * EPB;
#pragma unroll
        for (int u = 0; u < 16; ++u) {
            const int e = base + u * 256 + tid;
            if (e < ETOT) {
                const int dst = (e < NEDGE) ? ei[NEDGE + e] : (e - NEDGE);
                atomicAdd(&lcnt[dst >> 8], 1);
            }
        }
        __syncthreads();
        bcnt[bid * 256 + tid] = lcnt[tid];
    } else {
        const int g = (bid - NBIN) * 256 + tid;
        if (g < 256 * 64) {
            const int n = g >> 6, kk = g & 63;
            const float* W = (n < 128) ? Wl : Wr;
            const int nc = n & 127;
            const float a = W[(size_t)(2 * kk) * 128 + nc];
            const float b = W[(size_t)(2 * kk + 1) * 128 + nc];
            btg[g] = f2bf(a) | (f2bf(b) << 16);
        }
    }
}

// ============ K2: 2D scan -> per-block bases, bucket totals, bstart ============
__global__ __launch_bounds__(256) void scan_kernel(
    int* __restrict__ bcnt, int* __restrict__ gcnt,
    int* __restrict__ bstart, int* __restrict__ rowptr)
{
    __shared__ int wsum[4];
    const int t = threadIdx.x, lane = t & 63, wid = t >> 6;
    int run = 0;
    if (t < NBUCK) {
#pragma unroll 4
        for (int b = 0; b < NBIN; ++b) {
            const int idx = b * 256 + t;
            const int tmp = bcnt[idx];
            bcnt[idx] = run;          // becomes this block's base within bucket t
            run += tmp;
        }
        gcnt[t] = run;                // bucket total
    }
    int s = run;
#pragma unroll
    for (int off = 1; off < 64; off <<= 1) {
        int v = __shfl_up(s, off);
        if (lane >= off) s += v;
    }
    if (lane == 63) wsum[wid] = s;
    __syncthreads();
    if (t == 0) {
        int acc = 0;
#pragma unroll
        for (int w = 0; w < 4; ++w) { int v = wsum[w]; wsum[w] = acc; acc += v; }
    }
    __syncthreads();
    if (t < NBUCK) bstart[t] = wsum[wid] + s - run;   // exclusive bucket start
    if (t == 0) rowptr[N_NODES] = ETOT;
}

// ============ K3: binscatter (deterministic bases) || MFMA GEMM ============
__global__ __launch_bounds__(256) void k3_kernel(
    const float* __restrict__ x, const unsigned* __restrict__ btg,
    unsigned* __restrict__ xl_bf, unsigned* __restrict__ xr_bf,
    const int* __restrict__ ei, const int* __restrict__ bcnt,
    const int* __restrict__ bstart, unsigned* __restrict__ ebuf)
{
    __shared__ __align__(16) unsigned char smem[32768];
    const int bid = blockIdx.x;
    const int tid = threadIdx.x;

    if (bid < NBIN) {
        // ---- binscatter: one pass, no global atomics ----
        int* lcnt  = (int*)smem;          // [256]
        int* lbase = ((int*)smem) + 256;  // [256]
        lcnt[tid] = 0;
        if (tid < NBUCK) lbase[tid] = bstart[tid] + bcnt[bid * 256 + tid];
        __syncthreads();
        const int base = bid * EPB;
#pragma unroll
        for (int u = 0; u < 16; ++u) {
            const int e = base + u * 256 + tid;
            if (e < ETOT) {
                int s32, d32;
                if (e < NEDGE) { s32 = ei[e]; d32 = ei[NEDGE + e]; }
                else           { s32 = d32 = e - NEDGE; }
                const int b = d32 >> 8;
                const int p = lbase[b] + atomicAdd(&lcnt[b], 1);
                ebuf[p] = (unsigned)s32 | ((unsigned)(d32 & 255) << 16);   // src<65536
            }
        }
        return;
    }

    // ---- gemm tile ----
    unsigned char* Al = smem;
    unsigned char* Bl = smem + 16384;
    const int gb = bid - NBIN;
    const int nt = gb / MTILES;
    const int mt = gb % MTILES;
    const int mbase = mt * 64;
    const int nbase = nt * 64;

    {
        const int r = tid >> 2, q = tid & 3;
        int gm = mbase + r;
        gm = (gm < N_NODES) ? gm : (N_NODES - 1);
        const float* xrow = x + (size_t)gm * IN_CH + q * 32;
#pragma unroll
        for (int i = 0; i < 8; ++i) {
            const float4 xv = *(const float4*)(xrow + i * 4);
            uint2 p;
            p.x = f2bf(xv.x) | (f2bf(xv.y) << 16);
            p.y = f2bf(xv.z) | (f2bf(xv.w) << 16);
            *(uint2*)(Al + SWZ(r, q * 64 + i * 8)) = p;
        }
    }
    {
        const int r = tid >> 2, q = tid & 3;
        const unsigned* brow = btg + (size_t)(nbase + r) * 64 + q * 16;
#pragma unroll
        for (int i = 0; i < 4; ++i) {
            const uint4 v = *(const uint4*)(brow + i * 4);
            *(uint4*)(Bl + SWZ(r, q * 64 + i * 16)) = v;
        }
    }
    __syncthreads();

    const int l  = tid & 63;
    const int wv = tid >> 6;

    f32x4 acc[4];
#pragma unroll
    for (int n = 0; n < 4; ++n) acc[n] = (f32x4){0.f, 0.f, 0.f, 0.f};

    s16x8 af[4];
#pragma unroll
    for (int ks = 0; ks < 4; ++ks)
        af[ks] = *(const s16x8*)(Al + SWZ(wv * 16 + (l & 15), ks * 64 + (l >> 4) * 16));

#pragma unroll
    for (int nsub = 0; nsub < 4; ++nsub) {
#pragma unroll
        for (int ks = 0; ks < 4; ++ks) {
            const s16x8 bfr = *(const s16x8*)(Bl + SWZ(nsub * 16 + (l & 15), ks * 64 + (l >> 4) * 16));
            acc[nsub] = __builtin_amdgcn_mfma_f32_16x16x32_bf16(af[ks], bfr, acc[nsub], 0, 0, 0);
        }
    }

    unsigned* dstbuf = (nt < 2) ? xl_bf : xr_bf;
    const int ncol0 = (nt & 1) * 64;
#pragma unroll
    for (int nsub = 0; nsub < 4; ++nsub) {
        const int n = ncol0 + nsub * 16 + (l & 15);
#pragma unroll
        for (int reg = 0; reg < 4; ++reg) {
            const float v  = acc[nsub][reg];
            const float vp = __shfl_xor(v, 1);
            const int row = mbase + wv * 16 + (l >> 4) * 4 + reg;
            if (((l & 1) == 0) && row < N_NODES)
                dstbuf[(size_t)row * 64 + (n >> 1)] = f2bf(v) | (f2bf(vp) << 16);
        }
    }
}

// ============ K4: per-bucket place (rowptr + ssrc), LDS atomics only ============
__global__ __launch_bounds__(512) void place_kernel(
    const unsigned* __restrict__ ebuf, const int* __restrict__ gcnt,
    const int* __restrict__ bstart, int* __restrict__ rowptr, int* __restrict__ ssrc)
{
    __shared__ int lcnt[256];
    __shared__ int lcur[256];
    __shared__ int wsum[4];
    const int b = blockIdx.x;
    const int node0 = b << 8;
    const int estart = bstart[b];
    const int ecnt = gcnt[b];
    const int tid = threadIdx.x, lane = tid & 63, wid = tid >> 6;
    if (tid < 256) lcnt[tid] = 0;
    __syncthreads();
    for (int k = tid; k < ecnt; k += 512)
        atomicAdd(&lcnt[(ebuf[estart + k] >> 16) & 255], 1);
    __syncthreads();
    int v = 0, s = 0;
    if (tid < 256) {
        v = lcnt[tid]; s = v;
#pragma unroll
        for (int off = 1; off < 64; off <<= 1) {
            int t = __shfl_up(s, off);
            if (lane >= off) s += t;
        }
        if (lane == 63) wsum[wid] = s;
    }
    __syncthreads();
    if (tid == 0) {
        int acc = 0;
#pragma unroll
        for (int w = 0; w < 4; ++w) { int t = wsum[w]; wsum[w] = acc; acc += t; }
    }
    __syncthreads();
    if (tid < 256) {
        const int gpos = estart + wsum[wid] + s - v;
        const int node = node0 + tid;
        if (node < N_NODES) rowptr[node] = gpos;
        lcur[tid] = gpos;
    }
    __syncthreads();
    for (int k = tid; k < ecnt; k += 512) {
        const unsigned ed = ebuf[estart + k];
        const int p = atomicAdd(&lcur[(ed >> 16) & 255], 1);
        ssrc[p] = (int)(ed & 0xffffu);
    }
}

// ================= K5: fused attention + aggregate (one wave per dst) =========
// log2-domain scores (exp2 native), uniform masked batches (no tail loop).
#define RED4(a, b, cc, d) do { \
        a += __shfl_xor(a, 1); b += __shfl_xor(b, 1); cc += __shfl_xor(cc, 1); d += __shfl_xor(d, 1); \
        a += __shfl_xor(a, 2); b += __shfl_xor(b, 2); cc += __shfl_xor(cc, 2); d += __shfl_xor(d, 2); \
        a += __shfl_xor(a, 4); b += __shfl_xor(b, 4); cc += __shfl_xor(cc, 4); d += __shfl_xor(d, 4); \
        a += __shfl_xor(a, 8); b += __shfl_xor(b, 8); cc += __shfl_xor(cc, 8); d += __shfl_xor(d, 8); } while(0)

template<bool MASKED>
__device__ __forceinline__ void batch8(
    const int* __restrict__ srcs, int k, int k1, int lane,
    const unsigned* __restrict__ xl_bf,
    float xr2x, float xr2y, float a6x, float a4x, float a6y, float a4y,
    float& m, float& den, float& b0, float& b1)
{
#define KIDX(n) (MASKED ? min(k + n, k1 - 1) : (k + n))
#define LOADU(n) \
    const int j##n = __builtin_amdgcn_readfirstlane(srcs[KIDX(n)]); \
    const unsigned u##n = *(xl_bf + (size_t)j##n * 64 + lane);
    LOADU(0); LOADU(1); LOADU(2); LOADU(3);
    LOADU(4); LOADU(5); LOADU(6); LOADU(7);
#undef LOADU
#undef KIDX
#define SCORE(n) \
    const float t0_##n = bflo(u##n) + xr2x; \
    const float t1_##n = bfhi(u##n) + xr2y; \
    float s##n = fmaf(a6x, t0_##n, fmaf(a4x, fabsf(t0_##n), \
                 fmaf(a6y, t1_##n, a4y * fabsf(t1_##n))));
    SCORE(0); SCORE(1); SCORE(2); SCORE(3);
    SCORE(4); SCORE(5); SCORE(6); SCORE(7);
#undef SCORE
    RED4(s0, s1, s2, s3);
    RED4(s4, s5, s6, s7);
    if (MASKED) {
        const int r = k1 - k;     // valid slots, >=1
        s1 = (1 < r) ? s1 : -1e30f;
        s2 = (2 < r) ? s2 : -1e30f;
        s3 = (3 < r) ? s3 : -1e30f;
        s4 = (4 < r) ? s4 : -1e30f;
        s5 = (5 < r) ? s5 : -1e30f;
        s6 = (6 < r) ? s6 : -1e30f;
        s7 = (7 < r) ? s7 : -1e30f;
    }
    const float mx = fmaxf(fmaxf(fmaxf(s0, s1), fmaxf(s2, s3)),
                           fmaxf(fmaxf(s4, s5), fmaxf(s6, s7)));
    if (__any(mx > m)) {
        const float mn = fmaxf(mx, m);
        const float corr = (m == -INFINITY) ? 0.f : __builtin_amdgcn_exp2f(m - mn);
        den *= corr; b0 *= corr; b1 *= corr;
        m = mn;
    }
    const float p0 = __builtin_amdgcn_exp2f(s0 - m), p1 = __builtin_amdgcn_exp2f(s1 - m);
    const float p2 = __builtin_amdgcn_exp2f(s2 - m), p3 = __builtin_amdgcn_exp2f(s3 - m);
    const float p4 = __builtin_amdgcn_exp2f(s4 - m), p5 = __builtin_amdgcn_exp2f(s5 - m);
    const float p6 = __builtin_amdgcn_exp2f(s6 - m), p7 = __builtin_amdgcn_exp2f(s7 - m);
    den += ((p0 + p1) + (p2 + p3)) + ((p4 + p5) + (p6 + p7));
    b0 = fmaf(p0, t0_0, fmaf(p1, t0_1, fmaf(p2, t0_2, fmaf(p3, t0_3,
         fmaf(p4, t0_4, fmaf(p5, t0_5, fmaf(p6, t0_6, fmaf(p7, t0_7, b0))))))));
    b1 = fmaf(p0, t1_0, fmaf(p1, t1_1, fmaf(p2, t1_2, fmaf(p3, t1_3,
         fmaf(p4, t1_4, fmaf(p5, t1_5, fmaf(p6, t1_6, fmaf(p7, t1_7, b1))))))));
}

__global__ __launch_bounds__(256) void gat_kernel(
    const unsigned* __restrict__ xl_bf, const unsigned* __restrict__ xr_bf,
    const int* __restrict__ rowptr, const int* __restrict__ srcs,
    const float* __restrict__ att, const float* __restrict__ bias,
    float* __restrict__ out)
{
    const int lane = threadIdx.x & 63;
    const int i = blockIdx.x * 4 + (threadIdx.x >> 6);
    if (i >= N_NODES) return;
    const int c = lane * 2;
    const float2 att2 = *(const float2*)(att + c);
    const unsigned ur = xr_bf[(size_t)i * 64 + lane];
    const float xr2x = bflo(ur), xr2y = bfhi(ur);
    const float LOG2E = 1.4426950408889634f;
    const float a6x = 0.6f * att2.x * LOG2E, a4x = 0.4f * att2.x * LOG2E;
    const float a6y = 0.6f * att2.y * LOG2E, a4y = 0.4f * att2.y * LOG2E;
    const int k0 = rowptr[i], k1 = rowptr[i + 1];

    float m = -INFINITY, den = 0.f, b0 = 0.f, b1 = 0.f;
    int k = k0;
    for (; k + 8 <= k1; k += 8)
        batch8<false>(srcs, k, k1, lane, xl_bf, xr2x, xr2y,
                      a6x, a4x, a6y, a4y, m, den, b0, b1);
    if (k < k1)
        batch8<true>(srcs, k, k1, lane, xl_bf, xr2x, xr2y,
                     a6x, a4x, a6y, a4y, m, den, b0, b1);

    const float inv = 1.f / den;
    const float2 bb = *(const float2*)(bias + c);
    float2 o;
    o.x = fmaf(b0, inv, bb.x - xr2x);
    o.y = fmaf(b1, inv, bb.y - xr2y);
    *(float2*)(out + (size_t)i * TOT_CH + c) = o;
}

// ================= launch =================
extern "C" void kernel_launch(void* const* d_in, const int* in_sizes, int n_in,
                              void* d_out, int out_size, void* d_ws, size_t ws_size,
                              hipStream_t stream) {
    const float* x    = (const float*)d_in[0];
    const int*   ei   = (const int*)d_in[1];
    const float* Wl   = (const float*)d_in[2];
    const float* Wr   = (const float*)d_in[3];
    const float* att  = (const float*)d_in[4];
    const float* bias = (const float*)d_in[5];
    float* out = (float*)d_out;
    char*  ws  = (char*)d_ws;

    unsigned* xl_bf = (unsigned*)(ws + OFF_XL);
    unsigned* ebuf  = (unsigned*)(ws + OFF_EBUF);
    unsigned* xr_bf = (unsigned*)(ws + OFF_XR);
    int*   rowptr = (int*)(ws + OFF_ROWPTR);
    unsigned* btg = (unsigned*)(ws + OFF_BT);
    int*   ssrc   = (int*)(ws + OFF_SRC);
    int*   gcnt   = (int*)(ws + OFF_GCNT);
    int*   bstart = (int*)(ws + OFF_BSTART);
    int*   bcnt   = (int*)(ws + OFF_BCNT);

    // K1: binA (208) || wconv (64)
    hipLaunchKernelGGL(k1_kernel, dim3(NBIN + 64), dim3(256), 0, stream,
                       Wl, Wr, btg, ei, bcnt);
    // K2: scan
    hipLaunchKernelGGL(scan_kernel, dim3(1), dim3(256), 0, stream,
                       bcnt, gcnt, bstart, rowptr);
    // K3: binscatter (208, first) || gemm (3128)
    hipLaunchKernelGGL(k3_kernel, dim3(NBIN + MTILES * 4), dim3(256), 0, stream,
                       x, btg, xl_bf, xr_bf, ei, bcnt, bstart, ebuf);
    // K4: place
    hipLaunchKernelGGL(place_kernel, dim3(NBUCK), dim3(512), 0, stream,
                       ebuf, gcnt, bstart, rowptr, ssrc);
    // K5: gat
    hipLaunchKernelGGL(gat_kernel, dim3((N_NODES + 3) / 4), dim3(256), 0, stream,
                       xl_bf, xr_bf, rowptr, ssrc, att, bias, out);
}

// Round 12
// 106.203 us; speedup vs baseline: 1.8534x; 1.0659x over previous
//
#include <hip/hip_runtime.h>
#include <math.h>

#define N_NODES 50000
#define IN_CH   128
#define TOT_CH  128          // HEADS*OUT_CH
#define NEDGE   800000
#define ETOT    (NEDGE + N_NODES)
#define MTILES  ((N_NODES + 63) / 64)     // 782
#define NBUCK   ((N_NODES + 255) / 256)   // 196 buckets of 256 nodes
#define EPB     4096                       // edges per binning block
#define NBIN    ((ETOT + EPB - 1) / EPB)   // 208

// ---------------- workspace layout (bytes) ----------------
#define OFF_XL      ((size_t)0)                 // bf16 [N][128] = 12.8MB
#define OFF_EBUF    ((size_t)12800000)          // u32 [ETOT] = 3.4MB
#define OFF_XR      ((size_t)25600000)          // bf16 [N][128] = 12.8MB
#define OFF_ROWPTR  ((size_t)51200000)          // (N+1)*4
#define OFF_BT      ((size_t)51400064)          // Bt bf16-pairs 64KB
#define OFF_SRC     ((size_t)51800064)          // ETOT*4 = 3.4MB
#define OFF_GCNT    ((size_t)55200064)
#define OFF_BSTART  ((size_t)55201088)
#define OFF_BCNT    ((size_t)55203136)          // int [NBIN][256] = 213KB

typedef float f32x4 __attribute__((ext_vector_type(4)));
typedef short s16x8 __attribute__((ext_vector_type(8)));

__device__ __forceinline__ unsigned f2bf(float f) {   // RNE f32->bf16 bits
    unsigned u = __float_as_uint(f);
    return (u + 0x7fffu + ((u >> 16) & 1u)) >> 16;
}
__device__ __forceinline__ float bflo(unsigned u) { return __uint_as_float(u << 16); }
__device__ __forceinline__ float bfhi(unsigned u) { return __uint_as_float(u & 0xffff0000u); }

__device__ __forceinline__ int SWZ(int row, int byteoff) {
    return row * 256 + (byteoff ^ ((row & 7) << 4));
}

// ============ K1: binA (private per-block counts) || wconv ============
__global__ __launch_bounds__(256) void k1_kernel(
    const float* __restrict__ Wl, const float* __restrict__ Wr,
    unsigned* __restrict__ btg, const int* __restrict__ ei, int* __restrict__ bcnt)
{
    __shared__ int lcnt[256];
    const int bid = blockIdx.x;
    const int tid = threadIdx.x;
    if (bid < NBIN) {
        lcnt[tid] = 0;
        __syncthreads();
        const int base = bid * EPB;
#pragma unroll
        for (int u = 0; u < 16; ++u) {
            const int e = base + u * 256 + tid;
            if (e < ETOT) {
                const int dst = (e < NEDGE) ? ei[NEDGE + e] : (e - NEDGE);
                atomicAdd(&lcnt[dst >> 8], 1);
            }
        }
        __syncthreads();
        bcnt[bid * 256 + tid] = lcnt[tid];
    } else {
        const int g = (bid - NBIN) * 256 + tid;
        if (g < 256 * 64) {
            const int n = g >> 6, kk = g & 63;
            const float* W = (n < 128) ? Wl : Wr;
            const int nc = n & 127;
            const float a = W[(size_t)(2 * kk) * 128 + nc];
            const float b = W[(size_t)(2 * kk + 1) * 128 + nc];
            btg[g] = f2bf(a) | (f2bf(b) << 16);
        }
    }
}

// ============ K2: 2D scan -> per-block bases, bucket totals, bstart ============
__global__ __launch_bounds__(256) void scan_kernel(
    int* __restrict__ bcnt, int* __restrict__ gcnt,
    int* __restrict__ bstart, int* __restrict__ rowptr)
{
    __shared__ int wsum[4];
    const int t = threadIdx.x, lane = t & 63, wid = t >> 6;
    int run = 0;
    if (t < NBUCK) {
#pragma unroll 4
        for (int b = 0; b < NBIN; ++b) {
            const int idx = b * 256 + t;
            const int tmp = bcnt[idx];
            bcnt[idx] = run;          // becomes this block's base within bucket t
            run += tmp;
        }
        gcnt[t] = run;                // bucket total
    }
    int s = run;
#pragma unroll
    for (int off = 1; off < 64; off <<= 1) {
        int v = __shfl_up(s, off);
        if (lane >= off) s += v;
    }
    if (lane == 63) wsum[wid] = s;
    __syncthreads();
    if (t == 0) {
        int acc = 0;
#pragma unroll
        for (int w = 0; w < 4; ++w) { int v = wsum[w]; wsum[w] = acc; acc += v; }
    }
    __syncthreads();
    if (t < NBUCK) bstart[t] = wsum[wid] + s - run;   // exclusive bucket start
    if (t == 0) rowptr[N_NODES] = ETOT;
}

// ============ K3: binscatter (deterministic bases) || MFMA GEMM ============
__global__ __launch_bounds__(256) void k3_kernel(
    const float* __restrict__ x, const unsigned* __restrict__ btg,
    unsigned* __restrict__ xl_bf, unsigned* __restrict__ xr_bf,
    const int* __restrict__ ei, const int* __restrict__ bcnt,
    const int* __restrict__ bstart, unsigned* __restrict__ ebuf)
{
    __shared__ __align__(16) unsigned char smem[32768];
    const int bid = blockIdx.x;
    const int tid = threadIdx.x;

    if (bid < NBIN) {
        // ---- binscatter: one pass, no global atomics ----
        int* lcnt  = (int*)smem;          // [256]
        int* lbase = ((int*)smem) + 256;  // [256]
        lcnt[tid] = 0;
        if (tid < NBUCK) lbase[tid] = bstart[tid] + bcnt[bid * 256 + tid];
        __syncthreads();
        const int base = bid * EPB;
#pragma unroll
        for (int u = 0; u < 16; ++u) {
            const int e = base + u * 256 + tid;
            if (e < ETOT) {
                int s32, d32;
                if (e < NEDGE) { s32 = ei[e]; d32 = ei[NEDGE + e]; }
                else           { s32 = d32 = e - NEDGE; }
                const int b = d32 >> 8;
                const int p = lbase[b] + atomicAdd(&lcnt[b], 1);
                ebuf[p] = (unsigned)s32 | ((unsigned)(d32 & 255) << 16);   // src<65536
            }
        }
        return;
    }

    // ---- gemm tile ----
    unsigned char* Al = smem;
    unsigned char* Bl = smem + 16384;
    const int gb = bid - NBIN;
    const int nt = gb / MTILES;
    const int mt = gb % MTILES;
    const int mbase = mt * 64;
    const int nbase = nt * 64;

    {
        const int r = tid >> 2, q = tid & 3;
        int gm = mbase + r;
        gm = (gm < N_NODES) ? gm : (N_NODES - 1);
        const float* xrow = x + (size_t)gm * IN_CH + q * 32;
#pragma unroll
        for (int i = 0; i < 8; ++i) {
            const float4 xv = *(const float4*)(xrow + i * 4);
            uint2 p;
            p.x = f2bf(xv.x) | (f2bf(xv.y) << 16);
            p.y = f2bf(xv.z) | (f2bf(xv.w) << 16);
            *(uint2*)(Al + SWZ(r, q * 64 + i * 8)) = p;
        }
    }
    {
        const int r = tid >> 2, q = tid & 3;
        const unsigned* brow = btg + (size_t)(nbase + r) * 64 + q * 16;
#pragma unroll
        for (int i = 0; i < 4; ++i) {
            const uint4 v = *(const uint4*)(brow + i * 4);
            *(uint4*)(Bl + SWZ(r, q * 64 + i * 16)) = v;
        }
    }
    __syncthreads();

    const int l  = tid & 63;
    const int wv = tid >> 6;

    f32x4 acc[4];
#pragma unroll
    for (int n = 0; n < 4; ++n) acc[n] = (f32x4){0.f, 0.f, 0.f, 0.f};

    s16x8 af[4];
#pragma unroll
    for (int ks = 0; ks < 4; ++ks)
        af[ks] = *(const s16x8*)(Al + SWZ(wv * 16 + (l & 15), ks * 64 + (l >> 4) * 16));

#pragma unroll
    for (int nsub = 0; nsub < 4; ++nsub) {
#pragma unroll
        for (int ks = 0; ks < 4; ++ks) {
            const s16x8 bfr = *(const s16x8*)(Bl + SWZ(nsub * 16 + (l & 15), ks * 64 + (l >> 4) * 16));
            acc[nsub] = __builtin_amdgcn_mfma_f32_16x16x32_bf16(af[ks], bfr, acc[nsub], 0, 0, 0);
        }
    }

    unsigned* dstbuf = (nt < 2) ? xl_bf : xr_bf;
    const int ncol0 = (nt & 1) * 64;
#pragma unroll
    for (int nsub = 0; nsub < 4; ++nsub) {
        const int n = ncol0 + nsub * 16 + (l & 15);
#pragma unroll
        for (int reg = 0; reg < 4; ++reg) {
            const float v  = acc[nsub][reg];
            const float vp = __shfl_xor(v, 1);
            const int row = mbase + wv * 16 + (l >> 4) * 4 + reg;
            if (((l & 1) == 0) && row < N_NODES)
                dstbuf[(size_t)row * 64 + (n >> 1)] = f2bf(v) | (f2bf(vp) << 16);
        }
    }
}

// ============ K4: per-bucket place (rowptr + ssrc), LDS atomics only ============
__global__ __launch_bounds__(512) void place_kernel(
    const unsigned* __restrict__ ebuf, const int* __restrict__ gcnt,
    const int* __restrict__ bstart, int* __restrict__ rowptr, int* __restrict__ ssrc)
{
    __shared__ int lcnt[256];
    __shared__ int lcur[256];
    __shared__ int wsum[4];
    const int b = blockIdx.x;
    const int node0 = b << 8;
    const int estart = bstart[b];
    const int ecnt = gcnt[b];
    const int tid = threadIdx.x, lane = tid & 63, wid = tid >> 6;
    if (tid < 256) lcnt[tid] = 0;
    __syncthreads();
    for (int k = tid; k < ecnt; k += 512)
        atomicAdd(&lcnt[(ebuf[estart + k] >> 16) & 255], 1);
    __syncthreads();
    int v = 0, s = 0;
    if (tid < 256) {
        v = lcnt[tid]; s = v;
#pragma unroll
        for (int off = 1; off < 64; off <<= 1) {
            int t = __shfl_up(s, off);
            if (lane >= off) s += t;
        }
        if (lane == 63) wsum[wid] = s;
    }
    __syncthreads();
    if (tid == 0) {
        int acc = 0;
#pragma unroll
        for (int w = 0; w < 4; ++w) { int t = wsum[w]; wsum[w] = acc; acc += t; }
    }
    __syncthreads();
    if (tid < 256) {
        const int gpos = estart + wsum[wid] + s - v;
        const int node = node0 + tid;
        if (node < N_NODES) rowptr[node] = gpos;
        lcur[tid] = gpos;
    }
    __syncthreads();
    for (int k = tid; k < ecnt; k += 512) {
        const unsigned ed = ebuf[estart + k];
        const int p = atomicAdd(&lcur[(ed >> 16) & 255], 1);
        ssrc[p] = (int)(ed & 0xffffu);
    }
}

// ================= K5: fused attention + aggregate (one wave per dst) =========
// DPP butterfly reduce (no DS ops), no-max softmax (exp2 domain, |s| << 126),
// tree-form accumulation.
#define DPP_ADD(s, ctrl) do { \
        int _t = __builtin_amdgcn_update_dpp(0, __float_as_int(s), ctrl, 0xf, 0xf, true); \
        s += __int_as_float(_t); } while(0)

// 16-lane all-reduce: quad swap1, quad swap2, row_ror:4, row_ror:8
#define RED16x8(a0,a1,a2,a3,a4,a5,a6,a7) do { \
        DPP_ADD(a0,0xB1); DPP_ADD(a1,0xB1); DPP_ADD(a2,0xB1); DPP_ADD(a3,0xB1); \
        DPP_ADD(a4,0xB1); DPP_ADD(a5,0xB1); DPP_ADD(a6,0xB1); DPP_ADD(a7,0xB1); \
        DPP_ADD(a0,0x4E); DPP_ADD(a1,0x4E); DPP_ADD(a2,0x4E); DPP_ADD(a3,0x4E); \
        DPP_ADD(a4,0x4E); DPP_ADD(a5,0x4E); DPP_ADD(a6,0x4E); DPP_ADD(a7,0x4E); \
        DPP_ADD(a0,0x124); DPP_ADD(a1,0x124); DPP_ADD(a2,0x124); DPP_ADD(a3,0x124); \
        DPP_ADD(a4,0x124); DPP_ADD(a5,0x124); DPP_ADD(a6,0x124); DPP_ADD(a7,0x124); \
        DPP_ADD(a0,0x128); DPP_ADD(a1,0x128); DPP_ADD(a2,0x128); DPP_ADD(a3,0x128); \
        DPP_ADD(a4,0x128); DPP_ADD(a5,0x128); DPP_ADD(a6,0x128); DPP_ADD(a7,0x128); } while(0)

template<bool MASKED>
__device__ __forceinline__ void batch8(
    const int* __restrict__ srcs, int k, int k1, int lane,
    const unsigned* __restrict__ xl_bf,
    float xr2x, float xr2y, float a6x, float a4x, float a6y, float a4y,
    float& den, float& b0, float& b1)
{
#define KIDX(n) (MASKED ? min(k + n, k1 - 1) : (k + n))
#define LOADU(n) \
    const int j##n = __builtin_amdgcn_readfirstlane(srcs[KIDX(n)]); \
    const unsigned u##n = *(xl_bf + (size_t)j##n * 64 + lane);
    LOADU(0); LOADU(1); LOADU(2); LOADU(3);
    LOADU(4); LOADU(5); LOADU(6); LOADU(7);
#undef LOADU
#undef KIDX
#define SCORE(n) \
    const float t0_##n = bflo(u##n) + xr2x; \
    const float t1_##n = bfhi(u##n) + xr2y; \
    float s##n = fmaf(a6x, t0_##n, fmaf(a4x, fabsf(t0_##n), \
                 fmaf(a6y, t1_##n, a4y * fabsf(t1_##n))));
    SCORE(0); SCORE(1); SCORE(2); SCORE(3);
    SCORE(4); SCORE(5); SCORE(6); SCORE(7);
#undef SCORE
    RED16x8(s0, s1, s2, s3, s4, s5, s6, s7);
    if (MASKED) {
        const int r = k1 - k;     // valid slots, >=1
        s1 = (1 < r) ? s1 : -1e30f;
        s2 = (2 < r) ? s2 : -1e30f;
        s3 = (3 < r) ? s3 : -1e30f;
        s4 = (4 < r) ? s4 : -1e30f;
        s5 = (5 < r) ? s5 : -1e30f;
        s6 = (6 < r) ? s6 : -1e30f;
        s7 = (7 < r) ? s7 : -1e30f;
    }
    // no-max softmax: scores are O(1) in log2 domain, exp2 range is +-126
    const float p0 = __builtin_amdgcn_exp2f(s0), p1 = __builtin_amdgcn_exp2f(s1);
    const float p2 = __builtin_amdgcn_exp2f(s2), p3 = __builtin_amdgcn_exp2f(s3);
    const float p4 = __builtin_amdgcn_exp2f(s4), p5 = __builtin_amdgcn_exp2f(s5);
    const float p6 = __builtin_amdgcn_exp2f(s6), p7 = __builtin_amdgcn_exp2f(s7);
    den += ((p0 + p1) + (p2 + p3)) + ((p4 + p5) + (p6 + p7));
    {   // tree-form: 8 independent muls -> 4 fma -> 2 add -> 1 add
        const float e0 = fmaf(p1, t0_1, p0 * t0_0);
        const float e1 = fmaf(p3, t0_3, p2 * t0_2);
        const float e2 = fmaf(p5, t0_5, p4 * t0_4);
        const float e3 = fmaf(p7, t0_7, p6 * t0_6);
        b0 += (e0 + e1) + (e2 + e3);
        const float f0 = fmaf(p1, t1_1, p0 * t1_0);
        const float f1 = fmaf(p3, t1_3, p2 * t1_2);
        const float f2 = fmaf(p5, t1_5, p4 * t1_4);
        const float f3 = fmaf(p7, t1_7, p6 * t1_6);
        b1 += (f0 + f1) + (f2 + f3);
    }
}

__global__ __launch_bounds__(256) void gat_kernel(
    const unsigned* __restrict__ xl_bf, const unsigned* __restrict__ xr_bf,
    const int* __restrict__ rowptr, const int* __restrict__ srcs,
    const float* __restrict__ att, const float* __restrict__ bias,
    float* __restrict__ out)
{
    const int lane = threadIdx.x & 63;
    const int i = blockIdx.x * 4 + (threadIdx.x >> 6);
    if (i >= N_NODES) return;
    const int c = lane * 2;
    const float2 att2 = *(const float2*)(att + c);
    const unsigned ur = xr_bf[(size_t)i * 64 + lane];
    const float xr2x = bflo(ur), xr2y = bfhi(ur);
    const float LOG2E = 1.4426950408889634f;
    const float a6x = 0.6f * att2.x * LOG2E, a4x = 0.4f * att2.x * LOG2E;
    const float a6y = 0.6f * att2.y * LOG2E, a4y = 0.4f * att2.y * LOG2E;
    const int k0 = rowptr[i], k1 = rowptr[i + 1];

    float den = 0.f, b0 = 0.f, b1 = 0.f;
    int k = k0;
    for (; k + 8 <= k1; k += 8)
        batch8<false>(srcs, k, k1, lane, xl_bf, xr2x, xr2y,
                      a6x, a4x, a6y, a4y, den, b0, b1);
    if (k < k1)
        batch8<true>(srcs, k, k1, lane, xl_bf, xr2x, xr2y,
                     a6x, a4x, a6y, a4y, den, b0, b1);

    const float inv = 1.f / den;
    const float2 bb = *(const float2*)(bias + c);
    float2 o;
    o.x = fmaf(b0, inv, bb.x - xr2x);
    o.y = fmaf(b1, inv, bb.y - xr2y);
    *(float2*)(out + (size_t)i * TOT_CH + c) = o;
}

// ================= launch =================
extern "C" void kernel_launch(void* const* d_in, const int* in_sizes, int n_in,
                              void* d_out, int out_size, void* d_ws, size_t ws_size,
                              hipStream_t stream) {
    const float* x    = (const float*)d_in[0];
    const int*   ei   = (const int*)d_in[1];
    const float* Wl   = (const float*)d_in[2];
    const float* Wr   = (const float*)d_in[3];
    const float* att  = (const float*)d_in[4];
    const float* bias = (const float*)d_in[5];
    float* out = (float*)d_out;
    char*  ws  = (char*)d_ws;

    unsigned* xl_bf = (unsigned*)(ws + OFF_XL);
    unsigned* ebuf  = (unsigned*)(ws + OFF_EBUF);
    unsigned* xr_bf = (unsigned*)(ws + OFF_XR);
    int*   rowptr = (int*)(ws + OFF_ROWPTR);
    unsigned* btg = (unsigned*)(ws + OFF_BT);
    int*   ssrc   = (int*)(ws + OFF_SRC);
    int*   gcnt   = (int*)(ws + OFF_GCNT);
    int*   bstart = (int*)(ws + OFF_BSTART);
    int*   bcnt   = (int*)(ws + OFF_BCNT);

    // K1: binA (208) || wconv (64)
    hipLaunchKernelGGL(k1_kernel, dim3(NBIN + 64), dim3(256), 0, stream,
                       Wl, Wr, btg, ei, bcnt);
    // K2: scan
    hipLaunchKernelGGL(scan_kernel, dim3(1), dim3(256), 0, stream,
                       bcnt, gcnt, bstart, rowptr);
    // K3: binscatter (208, first) || gemm (3128)
    hipLaunchKernelGGL(k3_kernel, dim3(NBIN + MTILES * 4), dim3(256), 0, stream,
                       x, btg, xl_bf, xr_bf, ei, bcnt, bstart, ebuf);
    // K4: place
    hipLaunchKernelGGL(place_kernel, dim3(NBUCK), dim3(512), 0, stream,
                       ebuf, gcnt, bstart, rowptr, ssrc);
    // K5: gat
    hipLaunchKernelGGL(gat_kernel, dim3((N_NODES + 3) / 4), dim3(256), 0, stream,
                       xl_bf, xr_bf, rowptr, ssrc, att, bias, out);
}

// Round 13
// 91.814 us; speedup vs baseline: 2.1438x; 1.1567x over previous
//
#include <hip/hip_runtime.h>
#include <math.h>

#define N_NODES 50000
#define IN_CH   128
#define TOT_CH  128          // HEADS*OUT_CH
#define NEDGE   800000
#define ETOT    (NEDGE + N_NODES)
#define MTILES  ((N_NODES + 63) / 64)     // 782
#define NBUCK   ((N_NODES + 255) / 256)   // 196 buckets of 256 nodes
#define BCAP    8192                       // fixed slots per bucket (mean 4352, sigma 64)
#define EPB     4096                       // edges per binning block
#define NBIN    ((ETOT + EPB - 1) / EPB)   // 208

// ---------------- workspace layout (bytes) ----------------
#define OFF_XL      ((size_t)0)                 // bf16 [N][128] = 12.8MB
#define OFF_EBUF    ((size_t)12800000)          // u32 [NBUCK*BCAP] = 6.42MB
#define OFF_XR      ((size_t)25600000)          // bf16 [N][128] = 12.8MB
#define OFF_SRC     ((size_t)38400000)          // int [NBUCK*BCAP] = 6.42MB
#define OFF_BT      ((size_t)44900352)          // Bt bf16-pairs 64KB
#define OFF_GCUR    ((size_t)45000064)          // int [NBUCK]
#define OFF_ROWPTR  ((size_t)51200000)          // int2 [N] = 400KB

typedef float f32x4 __attribute__((ext_vector_type(4)));
typedef short s16x8 __attribute__((ext_vector_type(8)));

__device__ __forceinline__ unsigned f2bf(float f) {   // RNE f32->bf16 bits
    unsigned u = __float_as_uint(f);
    return (u + 0x7fffu + ((u >> 16) & 1u)) >> 16;
}
__device__ __forceinline__ float bflo(unsigned u) { return __uint_as_float(u << 16); }
__device__ __forceinline__ float bfhi(unsigned u) { return __uint_as_float(u & 0xffff0000u); }

__device__ __forceinline__ int SWZ(int row, int byteoff) {
    return row * 256 + (byteoff ^ ((row & 7) << 4));
}

// ============ K1: binscatter (fixed-capacity buckets) || wconv ============
__global__ __launch_bounds__(256) void k1_kernel(
    const float* __restrict__ Wl, const float* __restrict__ Wr,
    unsigned* __restrict__ btg, const int* __restrict__ ei,
    int* __restrict__ gcur, unsigned* __restrict__ ebuf)
{
    __shared__ int lcnt[256];
    __shared__ int lbase[256];
    const int bid = blockIdx.x;
    const int tid = threadIdx.x;

    if (bid < NBIN) {
        lcnt[tid] = 0;
        __syncthreads();
        const int base = bid * EPB;
        int sv[16], dv[16];
#pragma unroll
        for (int u = 0; u < 16; ++u) {
            const int e = base + u * 256 + tid;
            int s32 = 0, d32 = -1;
            if (e < ETOT) {
                if (e < NEDGE) { s32 = ei[e]; d32 = ei[NEDGE + e]; }
                else           { s32 = d32 = e - NEDGE; }
                atomicAdd(&lcnt[d32 >> 8], 1);
            }
            sv[u] = s32; dv[u] = d32;
        }
        __syncthreads();
        if (tid < NBUCK) {
            const int v = lcnt[tid];
            lbase[tid] = v ? atomicAdd(&gcur[tid], v) : 0;
        }
        __syncthreads();
        lcnt[tid] = 0;
        __syncthreads();
#pragma unroll
        for (int u = 0; u < 16; ++u) {
            const int d32 = dv[u];
            if (d32 >= 0) {
                const int b = d32 >> 8;
                const int p = lbase[b] + atomicAdd(&lcnt[b], 1);
                ebuf[b * BCAP + p] = (unsigned)sv[u] | ((unsigned)(d32 & 255) << 16);
            }
        }
    } else {
        const int g = (bid - NBIN) * 256 + tid;
        if (g < 256 * 64) {
            const int n = g >> 6, kk = g & 63;
            const float* W = (n < 128) ? Wl : Wr;
            const int nc = n & 127;
            const float a = W[(size_t)(2 * kk) * 128 + nc];
            const float b = W[(size_t)(2 * kk + 1) * 128 + nc];
            btg[g] = f2bf(a) | (f2bf(b) << 16);
        }
    }
}

// ============ K2: place (per-bucket rowptr2 + ssrc) || MFMA GEMM ============
__global__ __launch_bounds__(256) void k2_kernel(
    const float* __restrict__ x, const unsigned* __restrict__ btg,
    unsigned* __restrict__ xl_bf, unsigned* __restrict__ xr_bf,
    const unsigned* __restrict__ ebuf, const int* __restrict__ gcur,
    int2* __restrict__ rowptr2, int* __restrict__ ssrc)
{
    __shared__ __align__(16) unsigned char smem[32768];
    __shared__ int wsum[4];
    const int bid = blockIdx.x;
    const int tid = threadIdx.x;

    if (bid < NBUCK) {
        // ---- place: derive node ranges within padded bucket region ----
        int* lcnt = (int*)smem;          // [256]
        int* lcur = ((int*)smem) + 256;  // [256]
        const int ecnt  = gcur[bid];
        const int ebase = bid * BCAP;
        lcnt[tid] = 0;
        __syncthreads();
        for (int k = tid; k < ecnt; k += 256)
            atomicAdd(&lcnt[(ebuf[ebase + k] >> 16) & 255], 1);
        __syncthreads();
        const int lane = tid & 63, wid = tid >> 6;
        const int v = lcnt[tid];
        int s = v;
#pragma unroll
        for (int off = 1; off < 64; off <<= 1) {
            int t = __shfl_up(s, off);
            if (lane >= off) s += t;
        }
        if (lane == 63) wsum[wid] = s;
        __syncthreads();
        if (tid == 0) {
            int acc = 0;
#pragma unroll
            for (int w = 0; w < 4; ++w) { int t = wsum[w]; wsum[w] = acc; acc += t; }
        }
        __syncthreads();
        const int gpos = ebase + wsum[wid] + s - v;   // exclusive prefix in bucket
        const int node = (bid << 8) + tid;
        if (node < N_NODES) rowptr2[node] = make_int2(gpos, gpos + v);
        lcur[tid] = gpos;
        __syncthreads();
        for (int k = tid; k < ecnt; k += 256) {
            const unsigned ed = ebuf[ebase + k];
            const int p = atomicAdd(&lcur[(ed >> 16) & 255], 1);
            ssrc[p] = (int)(ed & 0xffffu);
        }
        return;
    }

    // ---- gemm tile ----
    unsigned char* Al = smem;
    unsigned char* Bl = smem + 16384;
    const int gb = bid - NBUCK;
    const int nt = gb / MTILES;
    const int mt = gb % MTILES;
    const int mbase = mt * 64;
    const int nbase = nt * 64;

    {
        const int r = tid >> 2, q = tid & 3;
        int gm = mbase + r;
        gm = (gm < N_NODES) ? gm : (N_NODES - 1);
        const float* xrow = x + (size_t)gm * IN_CH + q * 32;
#pragma unroll
        for (int i = 0; i < 8; ++i) {
            const float4 xv = *(const float4*)(xrow + i * 4);
            uint2 p;
            p.x = f2bf(xv.x) | (f2bf(xv.y) << 16);
            p.y = f2bf(xv.z) | (f2bf(xv.w) << 16);
            *(uint2*)(Al + SWZ(r, q * 64 + i * 8)) = p;
        }
    }
    {
        const int r = tid >> 2, q = tid & 3;
        const unsigned* brow = btg + (size_t)(nbase + r) * 64 + q * 16;
#pragma unroll
        for (int i = 0; i < 4; ++i) {
            const uint4 v = *(const uint4*)(brow + i * 4);
            *(uint4*)(Bl + SWZ(r, q * 64 + i * 16)) = v;
        }
    }
    __syncthreads();

    const int l  = tid & 63;
    const int wv = tid >> 6;

    f32x4 acc[4];
#pragma unroll
    for (int n = 0; n < 4; ++n) acc[n] = (f32x4){0.f, 0.f, 0.f, 0.f};

    s16x8 af[4];
#pragma unroll
    for (int ks = 0; ks < 4; ++ks)
        af[ks] = *(const s16x8*)(Al + SWZ(wv * 16 + (l & 15), ks * 64 + (l >> 4) * 16));

#pragma unroll
    for (int nsub = 0; nsub < 4; ++nsub) {
#pragma unroll
        for (int ks = 0; ks < 4; ++ks) {
            const s16x8 bfr = *(const s16x8*)(Bl + SWZ(nsub * 16 + (l & 15), ks * 64 + (l >> 4) * 16));
            acc[nsub] = __builtin_amdgcn_mfma_f32_16x16x32_bf16(af[ks], bfr, acc[nsub], 0, 0, 0);
        }
    }

    unsigned* dstbuf = (nt < 2) ? xl_bf : xr_bf;
    const int ncol0 = (nt & 1) * 64;
#pragma unroll
    for (int nsub = 0; nsub < 4; ++nsub) {
        const int n = ncol0 + nsub * 16 + (l & 15);
#pragma unroll
        for (int reg = 0; reg < 4; ++reg) {
            const float v  = acc[nsub][reg];
            const float vp = __shfl_xor(v, 1);
            const int row = mbase + wv * 16 + (l >> 4) * 4 + reg;
            if (((l & 1) == 0) && row < N_NODES)
                dstbuf[(size_t)row * 64 + (n >> 1)] = f2bf(v) | (f2bf(vp) << 16);
        }
    }
}

// ================= K3: fused attention + aggregate (one wave per dst) =========
#define DPP_ADD(s, ctrl) do { \
        int _t = __builtin_amdgcn_update_dpp(0, __float_as_int(s), ctrl, 0xf, 0xf, true); \
        s += __int_as_float(_t); } while(0)

#define RED16x8(a0,a1,a2,a3,a4,a5,a6,a7) do { \
        DPP_ADD(a0,0xB1); DPP_ADD(a1,0xB1); DPP_ADD(a2,0xB1); DPP_ADD(a3,0xB1); \
        DPP_ADD(a4,0xB1); DPP_ADD(a5,0xB1); DPP_ADD(a6,0xB1); DPP_ADD(a7,0xB1); \
        DPP_ADD(a0,0x4E); DPP_ADD(a1,0x4E); DPP_ADD(a2,0x4E); DPP_ADD(a3,0x4E); \
        DPP_ADD(a4,0x4E); DPP_ADD(a5,0x4E); DPP_ADD(a6,0x4E); DPP_ADD(a7,0x4E); \
        DPP_ADD(a0,0x124); DPP_ADD(a1,0x124); DPP_ADD(a2,0x124); DPP_ADD(a3,0x124); \
        DPP_ADD(a4,0x124); DPP_ADD(a5,0x124); DPP_ADD(a6,0x124); DPP_ADD(a7,0x124); \
        DPP_ADD(a0,0x128); DPP_ADD(a1,0x128); DPP_ADD(a2,0x128); DPP_ADD(a3,0x128); \
        DPP_ADD(a4,0x128); DPP_ADD(a5,0x128); DPP_ADD(a6,0x128); DPP_ADD(a7,0x128); } while(0)

template<bool MASKED>
__device__ __forceinline__ void batch8(
    const int* __restrict__ srcs, int k, int k1, int lane,
    const unsigned* __restrict__ xl_bf,
    float xr2x, float xr2y, float a6x, float a4x, float a6y, float a4y,
    float& den, float& b0, float& b1)
{
#define KIDX(n) (MASKED ? min(k + n, k1 - 1) : (k + n))
#define LOADU(n) \
    const int j##n = __builtin_amdgcn_readfirstlane(srcs[KIDX(n)]); \
    const unsigned u##n = *(xl_bf + (size_t)j##n * 64 + lane);
    LOADU(0); LOADU(1); LOADU(2); LOADU(3);
    LOADU(4); LOADU(5); LOADU(6); LOADU(7);
#undef LOADU
#undef KIDX
#define SCORE(n) \
    const float t0_##n = bflo(u##n) + xr2x; \
    const float t1_##n = bfhi(u##n) + xr2y; \
    float s##n = fmaf(a6x, t0_##n, fmaf(a4x, fabsf(t0_##n), \
                 fmaf(a6y, t1_##n, a4y * fabsf(t1_##n))));
    SCORE(0); SCORE(1); SCORE(2); SCORE(3);
    SCORE(4); SCORE(5); SCORE(6); SCORE(7);
#undef SCORE
    RED16x8(s0, s1, s2, s3, s4, s5, s6, s7);
    if (MASKED) {
        const int r = k1 - k;     // valid slots, >=1
        s1 = (1 < r) ? s1 : -1e30f;
        s2 = (2 < r) ? s2 : -1e30f;
        s3 = (3 < r) ? s3 : -1e30f;
        s4 = (4 < r) ? s4 : -1e30f;
        s5 = (5 < r) ? s5 : -1e30f;
        s6 = (6 < r) ? s6 : -1e30f;
        s7 = (7 < r) ? s7 : -1e30f;
    }
    const float p0 = __builtin_amdgcn_exp2f(s0), p1 = __builtin_amdgcn_exp2f(s1);
    const float p2 = __builtin_amdgcn_exp2f(s2), p3 = __builtin_amdgcn_exp2f(s3);
    const float p4 = __builtin_amdgcn_exp2f(s4), p5 = __builtin_amdgcn_exp2f(s5);
    const float p6 = __builtin_amdgcn_exp2f(s6), p7 = __builtin_amdgcn_exp2f(s7);
    den += ((p0 + p1) + (p2 + p3)) + ((p4 + p5) + (p6 + p7));
    {
        const float e0 = fmaf(p1, t0_1, p0 * t0_0);
        const float e1 = fmaf(p3, t0_3, p2 * t0_2);
        const float e2 = fmaf(p5, t0_5, p4 * t0_4);
        const float e3 = fmaf(p7, t0_7, p6 * t0_6);
        b0 += (e0 + e1) + (e2 + e3);
        const float f0 = fmaf(p1, t1_1, p0 * t1_0);
        const float f1 = fmaf(p3, t1_3, p2 * t1_2);
        const float f2 = fmaf(p5, t1_5, p4 * t1_4);
        const float f3 = fmaf(p7, t1_7, p6 * t1_6);
        b1 += (f0 + f1) + (f2 + f3);
    }
}

__global__ __launch_bounds__(256) void gat_kernel(
    const unsigned* __restrict__ xl_bf, const unsigned* __restrict__ xr_bf,
    const int2* __restrict__ rowptr2, const int* __restrict__ srcs,
    const float* __restrict__ att, const float* __restrict__ bias,
    float* __restrict__ out)
{
    const int lane = threadIdx.x & 63;
    const int i = blockIdx.x * 4 + (threadIdx.x >> 6);
    if (i >= N_NODES) return;
    const int c = lane * 2;
    const float2 att2 = *(const float2*)(att + c);
    const unsigned ur = xr_bf[(size_t)i * 64 + lane];
    const float xr2x = bflo(ur), xr2y = bfhi(ur);
    const float LOG2E = 1.4426950408889634f;
    const float a6x = 0.6f * att2.x * LOG2E, a4x = 0.4f * att2.x * LOG2E;
    const float a6y = 0.6f * att2.y * LOG2E, a4y = 0.4f * att2.y * LOG2E;
    const int2 kr = rowptr2[i];
    const int k0 = kr.x, k1 = kr.y;

    float den = 0.f, b0 = 0.f, b1 = 0.f;
    int k = k0;
    for (; k + 8 <= k1; k += 8)
        batch8<false>(srcs, k, k1, lane, xl_bf, xr2x, xr2y,
                      a6x, a4x, a6y, a4y, den, b0, b1);
    if (k < k1)
        batch8<true>(srcs, k, k1, lane, xl_bf, xr2x, xr2y,
                     a6x, a4x, a6y, a4y, den, b0, b1);

    const float inv = 1.f / den;
    const float2 bb = *(const float2*)(bias + c);
    float2 o;
    o.x = fmaf(b0, inv, bb.x - xr2x);
    o.y = fmaf(b1, inv, bb.y - xr2y);
    *(float2*)(out + (size_t)i * TOT_CH + c) = o;
}

// ================= launch =================
extern "C" void kernel_launch(void* const* d_in, const int* in_sizes, int n_in,
                              void* d_out, int out_size, void* d_ws, size_t ws_size,
                              hipStream_t stream) {
    const float* x    = (const float*)d_in[0];
    const int*   ei   = (const int*)d_in[1];
    const float* Wl   = (const float*)d_in[2];
    const float* Wr   = (const float*)d_in[3];
    const float* att  = (const float*)d_in[4];
    const float* bias = (const float*)d_in[5];
    float* out = (float*)d_out;
    char*  ws  = (char*)d_ws;

    unsigned* xl_bf = (unsigned*)(ws + OFF_XL);
    unsigned* ebuf  = (unsigned*)(ws + OFF_EBUF);
    unsigned* xr_bf = (unsigned*)(ws + OFF_XR);
    int*      ssrc  = (int*)(ws + OFF_SRC);
    unsigned* btg   = (unsigned*)(ws + OFF_BT);
    int*      gcur  = (int*)(ws + OFF_GCUR);
    int2*   rowptr2 = (int2*)(ws + OFF_ROWPTR);

    hipMemsetAsync(gcur, 0, NBUCK * sizeof(int), stream);
    // K1: binscatter (208) || wconv (64)
    hipLaunchKernelGGL(k1_kernel, dim3(NBIN + 64), dim3(256), 0, stream,
                       Wl, Wr, btg, ei, gcur, ebuf);
    // K2: place (196, first) || gemm (3128)
    hipLaunchKernelGGL(k2_kernel, dim3(NBUCK + MTILES * 4), dim3(256), 0, stream,
                       x, btg, xl_bf, xr_bf, ebuf, gcur, rowptr2, ssrc);
    // K3: gat
    hipLaunchKernelGGL(gat_kernel, dim3((N_NODES + 3) / 4), dim3(256), 0, stream,
                       xl_bf, xr_bf, rowptr2, ssrc, att, bias, out);
}

// Round 14
// 78.329 us; speedup vs baseline: 2.5129x; 1.1721x over previous
//
#include <hip/hip_runtime.h>
#include <math.h>

#define N_NODES 50000
#define IN_CH   128
#define TOT_CH  128          // HEADS*OUT_CH
#define NEDGE   800000
#define ETOT    (NEDGE + N_NODES)
#define MTILES  ((N_NODES + 63) / 64)     // 782
#define NBUCK   ((N_NODES + 255) / 256)   // 196 buckets of 256 nodes
#define BCAP    8192                       // fixed slots per bucket (mean 4352, sigma 66)
#define EPB     4096                       // edges per binning block
#define NBIN    ((ETOT + EPB - 1) / EPB)   // 208

// ---------------- workspace layout (bytes) ----------------
#define OFF_XL      ((size_t)0)                 // bf16 [N][128] = 12.8MB
#define OFF_EBUF    ((size_t)12800000)          // u32 [NBUCK*BCAP] = 6.42MB
#define OFF_XR      ((size_t)25600000)          // bf16 [N][128] = 12.8MB
#define OFF_SRC     ((size_t)38400000)          // int [NBUCK*BCAP] = 6.42MB
#define OFF_BT      ((size_t)44900352)          // Bt bf16-pairs 64KB
#define OFF_GCUR    ((size_t)45000064)          // int [NBUCK]
#define OFF_ROWPTR  ((size_t)51200000)          // int2 [N] = 400KB

typedef float f32x4 __attribute__((ext_vector_type(4)));
typedef short s16x8 __attribute__((ext_vector_type(8)));

__device__ __forceinline__ unsigned f2bf(float f) {   // RNE f32->bf16 bits
    unsigned u = __float_as_uint(f);
    return (u + 0x7fffu + ((u >> 16) & 1u)) >> 16;
}
__device__ __forceinline__ float bflo(unsigned u) { return __uint_as_float(u << 16); }
__device__ __forceinline__ float bfhi(unsigned u) { return __uint_as_float(u & 0xffff0000u); }

__device__ __forceinline__ int SWZ(int row, int byteoff) {
    return row * 256 + (byteoff ^ ((row & 7) << 4));
}

// ============ K1: binscatter (fixed-capacity buckets) || wconv ============
__global__ __launch_bounds__(256) void k1_kernel(
    const float* __restrict__ Wl, const float* __restrict__ Wr,
    unsigned* __restrict__ btg, const int* __restrict__ ei,
    int* __restrict__ gcur, unsigned* __restrict__ ebuf)
{
    __shared__ int lcnt[256];
    __shared__ int lbase[256];
    const int bid = blockIdx.x;
    const int tid = threadIdx.x;

    if (bid < NBIN) {
        lcnt[tid] = 0;
        __syncthreads();
        const int base = bid * EPB;
        int sv[16], dv[16];
#pragma unroll
        for (int u = 0; u < 16; ++u) {
            const int e = base + u * 256 + tid;
            int s32 = 0, d32 = -1;
            if (e < ETOT) {
                if (e < NEDGE) { s32 = ei[e]; d32 = ei[NEDGE + e]; }
                else           { s32 = d32 = e - NEDGE; }
                atomicAdd(&lcnt[d32 >> 8], 1);
            }
            sv[u] = s32; dv[u] = d32;
        }
        __syncthreads();
        if (tid < NBUCK) {
            const int v = lcnt[tid];
            lbase[tid] = v ? atomicAdd(&gcur[tid], v) : 0;
        }
        __syncthreads();
        lcnt[tid] = 0;
        __syncthreads();
#pragma unroll
        for (int u = 0; u < 16; ++u) {
            const int d32 = dv[u];
            if (d32 >= 0) {
                const int b = d32 >> 8;
                const int p = lbase[b] + atomicAdd(&lcnt[b], 1);
                ebuf[b * BCAP + p] = (unsigned)sv[u] | ((unsigned)(d32 & 255) << 16);
            }
        }
    } else {
        const int g = (bid - NBIN) * 256 + tid;
        if (g < 256 * 64) {
            const int n = g >> 6, kk = g & 63;
            const float* W = (n < 128) ? Wl : Wr;
            const int nc = n & 127;
            const float a = W[(size_t)(2 * kk) * 128 + nc];
            const float b = W[(size_t)(2 * kk + 1) * 128 + nc];
            btg[g] = f2bf(a) | (f2bf(b) << 16);
        }
    }
}

// ============ K2: place || MFMA GEMM (x read ONCE; n-loop inside block) ============
__global__ __launch_bounds__(256) void k2_kernel(
    const float* __restrict__ x, const unsigned* __restrict__ btg,
    unsigned* __restrict__ xl_bf, unsigned* __restrict__ xr_bf,
    const unsigned* __restrict__ ebuf, const int* __restrict__ gcur,
    int2* __restrict__ rowptr2, int* __restrict__ ssrc)
{
    __shared__ __align__(16) unsigned char smem[32768];
    __shared__ int wsum[4];
    const int bid = blockIdx.x;
    const int tid = threadIdx.x;

    if (bid < NBUCK) {
        // ---- place: derive node ranges within padded bucket region ----
        int* lcnt = (int*)smem;          // [256]
        int* lcur = ((int*)smem) + 256;  // [256]
        const int ecnt  = gcur[bid];
        const int ebase = bid * BCAP;
        lcnt[tid] = 0;
        __syncthreads();
        for (int k = tid; k < ecnt; k += 256)
            atomicAdd(&lcnt[(ebuf[ebase + k] >> 16) & 255], 1);
        __syncthreads();
        const int lane = tid & 63, wid = tid >> 6;
        const int v = lcnt[tid];
        int s = v;
#pragma unroll
        for (int off = 1; off < 64; off <<= 1) {
            int t = __shfl_up(s, off);
            if (lane >= off) s += t;
        }
        if (lane == 63) wsum[wid] = s;
        __syncthreads();
        if (tid == 0) {
            int acc = 0;
#pragma unroll
            for (int w = 0; w < 4; ++w) { int t = wsum[w]; wsum[w] = acc; acc += t; }
        }
        __syncthreads();
        const int gpos = ebase + wsum[wid] + s - v;   // exclusive prefix in bucket
        const int node = (bid << 8) + tid;
        if (node < N_NODES) rowptr2[node] = make_int2(gpos, gpos + v);
        lcur[tid] = gpos;
        __syncthreads();
        for (int k = tid; k < ecnt; k += 256) {
            const unsigned ed = ebuf[ebase + k];
            const int p = atomicAdd(&lcur[(ed >> 16) & 255], 1);
            ssrc[p] = (int)(ed & 0xffffu);
        }
        return;
    }

    // ---- gemm: one 64-row m-tile; loop over 4 n-subtiles (x staged ONCE) ----
    unsigned char* Al = smem;            // 16KB
    unsigned char* Bl = smem + 16384;    // 16KB (re-staged per n-tile)
    const int mt = bid - NBUCK;
    const int mbase = mt * 64;
    const int l  = tid & 63;
    const int wv = tid >> 6;

    {   // stage A (f32 -> bf16, swizzled) -- once
        const int r = tid >> 2, q = tid & 3;
        int gm = mbase + r;
        gm = (gm < N_NODES) ? gm : (N_NODES - 1);
        const float* xrow = x + (size_t)gm * IN_CH + q * 32;
#pragma unroll
        for (int i = 0; i < 8; ++i) {
            const float4 xv = *(const float4*)(xrow + i * 4);
            uint2 p;
            p.x = f2bf(xv.x) | (f2bf(xv.y) << 16);
            p.y = f2bf(xv.z) | (f2bf(xv.w) << 16);
            *(uint2*)(Al + SWZ(r, q * 64 + i * 8)) = p;
        }
    }
    {   // stage B tile 0
        const int r = tid >> 2, q = tid & 3;
        const unsigned* brow = btg + (size_t)r * 64 + q * 16;
#pragma unroll
        for (int i = 0; i < 4; ++i) {
            const uint4 v = *(const uint4*)(brow + i * 4);
            *(uint4*)(Bl + SWZ(r, q * 64 + i * 16)) = v;
        }
    }
    __syncthreads();

    s16x8 af[4];
#pragma unroll
    for (int ks = 0; ks < 4; ++ks)
        af[ks] = *(const s16x8*)(Al + SWZ(wv * 16 + (l & 15), ks * 64 + (l >> 4) * 16));

    for (int nt4 = 0; nt4 < 4; ++nt4) {
        f32x4 acc[4];
#pragma unroll
        for (int n = 0; n < 4; ++n) acc[n] = (f32x4){0.f, 0.f, 0.f, 0.f};
#pragma unroll
        for (int nsub = 0; nsub < 4; ++nsub) {
#pragma unroll
            for (int ks = 0; ks < 4; ++ks) {
                const s16x8 bfr = *(const s16x8*)(Bl + SWZ(nsub * 16 + (l & 15), ks * 64 + (l >> 4) * 16));
                acc[nsub] = __builtin_amdgcn_mfma_f32_16x16x32_bf16(af[ks], bfr, acc[nsub], 0, 0, 0);
            }
        }
        // epilogue for this 64-col tile
        unsigned* dstbuf = (nt4 < 2) ? xl_bf : xr_bf;
        const int ncol0 = (nt4 & 1) * 64;
#pragma unroll
        for (int nsub = 0; nsub < 4; ++nsub) {
            const int n = ncol0 + nsub * 16 + (l & 15);
#pragma unroll
            for (int reg = 0; reg < 4; ++reg) {
                const float v  = acc[nsub][reg];
                const float vp = __shfl_xor(v, 1);
                const int row = mbase + wv * 16 + (l >> 4) * 4 + reg;
                if (((l & 1) == 0) && row < N_NODES)
                    dstbuf[(size_t)row * 64 + (n >> 1)] = f2bf(v) | (f2bf(vp) << 16);
            }
        }
        if (nt4 == 3) break;
        __syncthreads();   // all waves done reading Bl
        {   // stage B tile nt4+1
            const int r = tid >> 2, q = tid & 3;
            const unsigned* brow = btg + (size_t)((nt4 + 1) * 64 + r) * 64 + q * 16;
#pragma unroll
            for (int i = 0; i < 4; ++i) {
                const uint4 v = *(const uint4*)(brow + i * 4);
                *(uint4*)(Bl + SWZ(r, q * 64 + i * 16)) = v;
            }
        }
        __syncthreads();
    }
}

// ================= K3: fused attention + aggregate (one wave per dst) =========
#define DPP_ADD(s, ctrl) do { \
        int _t = __builtin_amdgcn_update_dpp(0, __float_as_int(s), ctrl, 0xf, 0xf, true); \
        s += __int_as_float(_t); } while(0)

#define RED16x8(a0,a1,a2,a3,a4,a5,a6,a7) do { \
        DPP_ADD(a0,0xB1); DPP_ADD(a1,0xB1); DPP_ADD(a2,0xB1); DPP_ADD(a3,0xB1); \
        DPP_ADD(a4,0xB1); DPP_ADD(a5,0xB1); DPP_ADD(a6,0xB1); DPP_ADD(a7,0xB1); \
        DPP_ADD(a0,0x4E); DPP_ADD(a1,0x4E); DPP_ADD(a2,0x4E); DPP_ADD(a3,0x4E); \
        DPP_ADD(a4,0x4E); DPP_ADD(a5,0x4E); DPP_ADD(a6,0x4E); DPP_ADD(a7,0x4E); \
        DPP_ADD(a0,0x124); DPP_ADD(a1,0x124); DPP_ADD(a2,0x124); DPP_ADD(a3,0x124); \
        DPP_ADD(a4,0x124); DPP_ADD(a5,0x124); DPP_ADD(a6,0x124); DPP_ADD(a7,0x124); \
        DPP_ADD(a0,0x128); DPP_ADD(a1,0x128); DPP_ADD(a2,0x128); DPP_ADD(a3,0x128); \
        DPP_ADD(a4,0x128); DPP_ADD(a5,0x128); DPP_ADD(a6,0x128); DPP_ADD(a7,0x128); } while(0)

template<bool MASKED>
__device__ __forceinline__ void batch8(
    const int* __restrict__ srcs, int k, int k1, int lane,
    const unsigned* __restrict__ xl_bf,
    float xr2x, float xr2y, float a6x, float a4x, float a6y, float a4y,
    float& den, float& b0, float& b1)
{
#define KIDX(n) (MASKED ? min(k + n, k1 - 1) : (k + n))
#define LOADU(n) \
    const int j##n = __builtin_amdgcn_readfirstlane(srcs[KIDX(n)]); \
    const unsigned u##n = *(xl_bf + (size_t)j##n * 64 + lane);
    LOADU(0); LOADU(1); LOADU(2); LOADU(3);
    LOADU(4); LOADU(5); LOADU(6); LOADU(7);
#undef LOADU
#undef KIDX
#define SCORE(n) \
    const float t0_##n = bflo(u##n) + xr2x; \
    const float t1_##n = bfhi(u##n) + xr2y; \
    float s##n = fmaf(a6x, t0_##n, fmaf(a4x, fabsf(t0_##n), \
                 fmaf(a6y, t1_##n, a4y * fabsf(t1_##n))));
    SCORE(0); SCORE(1); SCORE(2); SCORE(3);
    SCORE(4); SCORE(5); SCORE(6); SCORE(7);
#undef SCORE
    RED16x8(s0, s1, s2, s3, s4, s5, s6, s7);
    if (MASKED) {
        const int r = k1 - k;     // valid slots, >=1
        s1 = (1 < r) ? s1 : -1e30f;
        s2 = (2 < r) ? s2 : -1e30f;
        s3 = (3 < r) ? s3 : -1e30f;
        s4 = (4 < r) ? s4 : -1e30f;
        s5 = (5 < r) ? s5 : -1e30f;
        s6 = (6 < r) ? s6 : -1e30f;
        s7 = (7 < r) ? s7 : -1e30f;
    }
    const float p0 = __builtin_amdgcn_exp2f(s0), p1 = __builtin_amdgcn_exp2f(s1);
    const float p2 = __builtin_amdgcn_exp2f(s2), p3 = __builtin_amdgcn_exp2f(s3);
    const float p4 = __builtin_amdgcn_exp2f(s4), p5 = __builtin_amdgcn_exp2f(s5);
    const float p6 = __builtin_amdgcn_exp2f(s6), p7 = __builtin_amdgcn_exp2f(s7);
    den += ((p0 + p1) + (p2 + p3)) + ((p4 + p5) + (p6 + p7));
    {
        const float e0 = fmaf(p1, t0_1, p0 * t0_0);
        const float e1 = fmaf(p3, t0_3, p2 * t0_2);
        const float e2 = fmaf(p5, t0_5, p4 * t0_4);
        const float e3 = fmaf(p7, t0_7, p6 * t0_6);
        b0 += (e0 + e1) + (e2 + e3);
        const float f0 = fmaf(p1, t1_1, p0 * t1_0);
        const float f1 = fmaf(p3, t1_3, p2 * t1_2);
        const float f2 = fmaf(p5, t1_5, p4 * t1_4);
        const float f3 = fmaf(p7, t1_7, p6 * t1_6);
        b1 += (f0 + f1) + (f2 + f3);
    }
}

__global__ __launch_bounds__(256) void gat_kernel(
    const unsigned* __restrict__ xl_bf, const unsigned* __restrict__ xr_bf,
    const int2* __restrict__ rowptr2, const int* __restrict__ srcs,
    const float* __restrict__ att, const float* __restrict__ bias,
    float* __restrict__ out)
{
    const int lane = threadIdx.x & 63;
    const int i = blockIdx.x * 4 + (threadIdx.x >> 6);
    if (i >= N_NODES) return;
    const int c = lane * 2;
    const float2 att2 = *(const float2*)(att + c);
    const unsigned ur = xr_bf[(size_t)i * 64 + lane];
    const float xr2x = bflo(ur), xr2y = bfhi(ur);
    const float LOG2E = 1.4426950408889634f;
    const float a6x = 0.6f * att2.x * LOG2E, a4x = 0.4f * att2.x * LOG2E;
    const float a6y = 0.6f * att2.y * LOG2E, a4y = 0.4f * att2.y * LOG2E;
    const int2 kr = rowptr2[i];
    const int k0 = __builtin_amdgcn_readfirstlane(kr.x);   // scalarize -> s_load path
    const int k1 = __builtin_amdgcn_readfirstlane(kr.y);

    float den = 0.f, b0 = 0.f, b1 = 0.f;
    int k = k0;
    for (; k + 8 <= k1; k += 8)
        batch8<false>(srcs, k, k1, lane, xl_bf, xr2x, xr2y,
                      a6x, a4x, a6y, a4y, den, b0, b1);
    if (k < k1)
        batch8<true>(srcs, k, k1, lane, xl_bf, xr2x, xr2y,
                     a6x, a4x, a6y, a4y, den, b0, b1);

    const float inv = 1.f / den;
    const float2 bb = *(const float2*)(bias + c);
    float2 o;
    o.x = fmaf(b0, inv, bb.x - xr2x);
    o.y = fmaf(b1, inv, bb.y - xr2y);
    *(float2*)(out + (size_t)i * TOT_CH + c) = o;
}

// ================= launch =================
extern "C" void kernel_launch(void* const* d_in, const int* in_sizes, int n_in,
                              void* d_out, int out_size, void* d_ws, size_t ws_size,
                              hipStream_t stream) {
    const float* x    = (const float*)d_in[0];
    const int*   ei   = (const int*)d_in[1];
    const float* Wl   = (const float*)d_in[2];
    const float* Wr   = (const float*)d_in[3];
    const float* att  = (const float*)d_in[4];
    const float* bias = (const float*)d_in[5];
    float* out = (float*)d_out;
    char*  ws  = (char*)d_ws;

    unsigned* xl_bf = (unsigned*)(ws + OFF_XL);
    unsigned* ebuf  = (unsigned*)(ws + OFF_EBUF);
    unsigned* xr_bf = (unsigned*)(ws + OFF_XR);
    int*      ssrc  = (int*)(ws + OFF_SRC);
    unsigned* btg   = (unsigned*)(ws + OFF_BT);
    int*      gcur  = (int*)(ws + OFF_GCUR);
    int2*   rowptr2 = (int2*)(ws + OFF_ROWPTR);

    hipMemsetAsync(gcur, 0, NBUCK * sizeof(int), stream);
    // K1: binscatter (208) || wconv (64)
    hipLaunchKernelGGL(k1_kernel, dim3(NBIN + 64), dim3(256), 0, stream,
                       Wl, Wr, btg, ei, gcur, ebuf);
    // K2: place (196, first) || gemm (782, x staged once per m-tile)
    hipLaunchKernelGGL(k2_kernel, dim3(NBUCK + MTILES), dim3(256), 0, stream,
                       x, btg, xl_bf, xr_bf, ebuf, gcur, rowptr2, ssrc);
    // K3: gat
    hipLaunchKernelGGL(gat_kernel, dim3((N_NODES + 3) / 4), dim3(256), 0, stream,
                       xl_bf, xr_bf, rowptr2, ssrc, att, bias, out);
}